// Round 13
// baseline (965.932 us; speedup 1.0000x reference)
//
#include <hip/hip_runtime.h>

// Problem constants: B=32, S=512, L=20, T=16, E=300, H=128, D=128, V=50000

// Raw workgroup barrier: orders LDS ops (lgkmcnt drain) but does NOT drain
// vmcnt — keeps prefetch global-loads and fire-and-forget stores in flight.
#define LDS_BARRIER() do {                                   \
    asm volatile("s_waitcnt lgkmcnt(0)" ::: "memory");       \
    __builtin_amdgcn_s_barrier();                            \
    asm volatile("" ::: "memory");                           \
  } while (0)

// AGPR residency (round-12 insight): the allocator refuses to keep weight
// floats in VGPRs (pinned at 88 across rounds 5-11, re-streaming 196 KB/step
// from L2 at the ~128 B/cyc per-CU refill path = the 1640-cyc step wall).
// "a"-constrained asm forces values into the unified file's AGPR class —
// no remat possible, zero per-step weight memory traffic.
#define AGPR_WRITE(dst, src) \
  asm volatile("v_accvgpr_write_b32 %0, %1" : "=a"(dst) : "v"(src))
#define AGPR_READ(dst, src) \
  asm volatile("v_accvgpr_read_b32 %0, %1" : "=v"(dst) : "a"(src))

// ---------------------------------------------------------------------------
// K0: concatenate GRU input-gate weights/biases: Wcat (768,300) = [Wi_f;Wi_b],
// bcat (768) = [bi_f;bi_b].  grid = 450 x 256.
// ---------------------------------------------------------------------------
__global__ __launch_bounds__(256) void k_wcat(
    const float* __restrict__ wf, const float* __restrict__ wb,
    const float* __restrict__ bf, const float* __restrict__ bb,
    float* __restrict__ Wcat, float* __restrict__ bcat)
{
  const int idx = blockIdx.x * 256 + threadIdx.x;   // 0 .. 115199
  Wcat[idx] = wf[idx];
  Wcat[115200 + idx] = wb[idx];
  if (idx < 384) { bcat[idx] = bf[idx]; bcat[384 + idx] = bb[idx]; }
}

// ---------------------------------------------------------------------------
// K1: sentence embedding mean, float4 loads.  grid = B*S blocks, 128 threads.
// ---------------------------------------------------------------------------
__global__ __launch_bounds__(128) void k_sent_mean(
    const int* __restrict__ wid, const float* __restrict__ emb,
    float* __restrict__ sent)
{
  const int bs = blockIdx.x;
  const int t = threadIdx.x;
  const int* w = wid + (size_t)bs * 20;
  if (t >= 75) return;
  float4 a = {0.f, 0.f, 0.f, 0.f};
  for (int l = 0; l < 20; ++l) {
    const float4 v = *(const float4*)(emb + (size_t)w[l] * 300 + t * 4);
    a.x += v.x; a.y += v.y; a.z += v.z; a.w += v.w;
  }
  const float inv = 1.0f / 20.0f;
  a.x *= inv; a.y *= inv; a.z *= inv; a.w *= inv;
  *(float4*)(sent + (size_t)bs * 300 + t * 4) = a;
}

// ---------------------------------------------------------------------------
// K2 v3: fp32 tiled GEMM, 128x128 tile, 8x8 micro-tile (split 4+4 so LDS
// reads are 16B-stride across 16 lanes = 2-way bank aliasing = free), BK=32.
// Per-kk per-wave: 4 ds_read_b128 + 64 FMA (v2 was 2 reads + 16 FMA ->
// LDS-instruction-bound at ~50 TF; v3 ~2x better fed).
// C[M,N] = A[M,K] @ B + bias, optional relu.
// BT=true : B is (N,K) row-major -> C=A@B^T ;  BT=false: B is (K,N) -> C=A@B
// N must be a multiple of 128 at call sites; M,K arbitrary.
// ---------------------------------------------------------------------------
template<bool BT, int ACT>
__global__ __launch_bounds__(256) void k_gemm(
    const int M, const int N, const int K,
    const float* __restrict__ A, const int lda,
    const float* __restrict__ Bm, const int ldb,
    float* __restrict__ C, const int ldc,
    const float* __restrict__ bias)
{
  (void)N;
  __shared__ float Ast[32][132];   // [k][m] transposed; 132*4=528B rows (16B-aligned)
  __shared__ float Bs[32][132];    // [k][n]
  const int tid = threadIdx.x;
  const int m0 = blockIdx.x * 128;
  const int n0 = blockIdx.y * 128;
  const int tx = tid & 15;         // n-dir, 16 values
  const int ty = tid >> 4;         // m-dir, 16 values
  float acc[2][4][2][4] = {};      // [ih][i][jh][j]: row ih*64+ty*4+i, col jh*64+tx*4+j

  for (int kc = 0; kc < K; kc += 32) {
    const int kb = (K - kc < 32) ? (K - kc) : 32;
    // --- stage A tile transposed: 1024 float4, f = j*256+tid ---
    #pragma unroll
    for (int j = 0; j < 4; ++j) {
      const int f = j * 256 + tid;
      const int m = f >> 3;
      const int k4 = (f & 7) * 4;
      float4 v = make_float4(0.f, 0.f, 0.f, 0.f);
      if (m0 + m < M) {
        const float* ap = A + (size_t)(m0 + m) * lda + kc;
        if (k4 + 4 <= kb) {
          v = *(const float4*)(ap + k4);
        } else {
          if (k4 + 0 < kb) v.x = ap[k4 + 0];
          if (k4 + 1 < kb) v.y = ap[k4 + 1];
          if (k4 + 2 < kb) v.z = ap[k4 + 2];
          if (k4 + 3 < kb) v.w = ap[k4 + 3];
        }
      }
      Ast[k4 + 0][m] = v.x;
      Ast[k4 + 1][m] = v.y;
      Ast[k4 + 2][m] = v.z;
      Ast[k4 + 3][m] = v.w;
    }
    // --- stage B tile: Bs[k][n] ---
    if (BT) {
      #pragma unroll
      for (int j = 0; j < 4; ++j) {
        const int f = j * 256 + tid;
        const int n = f >> 3;                 // n0+n < N (N % 128 == 0)
        const int k4 = (f & 7) * 4;
        float4 v = make_float4(0.f, 0.f, 0.f, 0.f);
        const float* bp = Bm + (size_t)(n0 + n) * ldb + kc;
        if (k4 + 4 <= kb) {
          v = *(const float4*)(bp + k4);
        } else {
          if (k4 + 0 < kb) v.x = bp[k4 + 0];
          if (k4 + 1 < kb) v.y = bp[k4 + 1];
          if (k4 + 2 < kb) v.z = bp[k4 + 2];
          if (k4 + 3 < kb) v.w = bp[k4 + 3];
        }
        Bs[k4 + 0][n] = v.x;
        Bs[k4 + 1][n] = v.y;
        Bs[k4 + 2][n] = v.z;
        Bs[k4 + 3][n] = v.w;
      }
    } else {
      #pragma unroll
      for (int j = 0; j < 4; ++j) {
        const int f = j * 256 + tid;
        const int kk = f >> 5;
        const int n4 = (f & 31) * 4;
        float4 v = make_float4(0.f, 0.f, 0.f, 0.f);
        if (kk < kb) v = *(const float4*)(Bm + (size_t)(kc + kk) * ldb + n0 + n4);
        *(float4*)&Bs[kk][n4] = v;
      }
    }
    __syncthreads();
    #pragma unroll 2
    for (int kk = 0; kk < kb; ++kk) {
      const float4 a0 = *(const float4*)&Ast[kk][ty * 4];
      const float4 a1 = *(const float4*)&Ast[kk][64 + ty * 4];
      const float4 b0 = *(const float4*)&Bs[kk][tx * 4];
      const float4 b1 = *(const float4*)&Bs[kk][64 + tx * 4];
      const float av[2][4] = {{a0.x, a0.y, a0.z, a0.w}, {a1.x, a1.y, a1.z, a1.w}};
      const float bv[2][4] = {{b0.x, b0.y, b0.z, b0.w}, {b1.x, b1.y, b1.z, b1.w}};
      #pragma unroll
      for (int ih = 0; ih < 2; ++ih)
        #pragma unroll
        for (int i = 0; i < 4; ++i)
          #pragma unroll
          for (int jh = 0; jh < 2; ++jh)
            #pragma unroll
            for (int j = 0; j < 4; ++j)
              acc[ih][i][jh][j] = fmaf(av[ih][i], bv[jh][j], acc[ih][i][jh][j]);
    }
    __syncthreads();
  }

  float bv4[2][4] = {};
  if (bias != nullptr) {
    #pragma unroll
    for (int jh = 0; jh < 2; ++jh)
      #pragma unroll
      for (int j = 0; j < 4; ++j)
        bv4[jh][j] = bias[n0 + jh * 64 + tx * 4 + j];
  }
  #pragma unroll
  for (int ih = 0; ih < 2; ++ih)
    #pragma unroll
    for (int i = 0; i < 4; ++i) {
      const int m = m0 + ih * 64 + ty * 4 + i;
      if (m < M) {
        #pragma unroll
        for (int jh = 0; jh < 2; ++jh) {
          float4 o;
          o.x = acc[ih][i][jh][0] + bv4[jh][0];
          o.y = acc[ih][i][jh][1] + bv4[jh][1];
          o.z = acc[ih][i][jh][2] + bv4[jh][2];
          o.w = acc[ih][i][jh][3] + bv4[jh][3];
          if (ACT == 1) {
            o.x = fmaxf(o.x, 0.f); o.y = fmaxf(o.y, 0.f);
            o.z = fmaxf(o.z, 0.f); o.w = fmaxf(o.w, 0.f);
          }
          *(float4*)&C[(size_t)m * ldc + n0 + jh * 64 + tx * 4] = o;
        }
      }
    }
}

// ---------------------------------------------------------------------------
// K3: GRU recurrence — round-6/12 structure with AGPR-RESIDENT WEIGHTS.
// grid = 64, 512 thr.  8 waves; wave wv: kq=wv&3 (K-quarter), rg=wv>>2 (row
// half); lane owns rows r0=rg*192+ln, +64, +128 x its 32-float K-slice =
// 96 weight floats, held in 96 AGPRs via v_accvgpr_write (prologue) and read
// back per step via v_accvgpr_read (96 read + 96 FMA per lane per step —
// pure VALU, no weight memory traffic).  partl[4][384]; 2 barriers/step;
// 32-step gi chunks (stride-768 fused buffer) via register staging.
// Accumulation order identical to round 6 -> absmax should stay 0.5.
// ---------------------------------------------------------------------------
__global__ __launch_bounds__(512, 2) void k_gru(
    const float* __restrict__ gi_fb,
    const float* __restrict__ Wh_f, const float* __restrict__ Wh_b,
    const float* __restrict__ bh_f, const float* __restrict__ bh_b,
    float* __restrict__ srep, float* __restrict__ hfin)
{
  const int dir = blockIdx.x & 1;
  const int b = blockIdx.x >> 1;
  const float* gi = gi_fb + (size_t)b * 512 * 768 + dir * 384;  // row stride 768
  const float* Wh = dir ? Wh_b : Wh_f;
  const float* bh = dir ? bh_b : bh_f;

  const int tid = threadIdx.x;
  const int wv = tid >> 6;
  const int ln = tid & 63;
  const int kq = wv & 3;          // K-quarter: h floats kq*32 .. kq*32+31
  const int rg = wv >> 2;         // row half: rows rg*192 .. rg*192+191
  const int r0 = rg * 192 + ln;   // this lane's rows: r0, r0+64, r0+128

  __shared__ __align__(16) float hlds[128];
  __shared__ float partl[4 * 384];                   // [kq][row], stride-1 rows
  __shared__ __align__(16) float gis[2][32 * 384];   // 2 x 48 KB

  // --- load 96 weight floats/lane and pin them into AGPRs ---
  float aw0[32], aw1[32], aw2[32];
  {
    const float* p = Wh + (size_t)r0 * 128 + kq * 32;
    #pragma unroll
    for (int k = 0; k < 32; k += 4) {
      const float4 v = *(const float4*)(p + k);
      AGPR_WRITE(aw0[k + 0], v.x); AGPR_WRITE(aw0[k + 1], v.y);
      AGPR_WRITE(aw0[k + 2], v.z); AGPR_WRITE(aw0[k + 3], v.w);
    }
    p += 64 * 128;
    #pragma unroll
    for (int k = 0; k < 32; k += 4) {
      const float4 v = *(const float4*)(p + k);
      AGPR_WRITE(aw1[k + 0], v.x); AGPR_WRITE(aw1[k + 1], v.y);
      AGPR_WRITE(aw1[k + 2], v.z); AGPR_WRITE(aw1[k + 3], v.w);
    }
    p += 64 * 128;
    #pragma unroll
    for (int k = 0; k < 32; k += 4) {
      const float4 v = *(const float4*)(p + k);
      AGPR_WRITE(aw2[k + 0], v.x); AGPR_WRITE(aw2[k + 1], v.y);
      AGPR_WRITE(aw2[k + 2], v.z); AGPR_WRITE(aw2[k + 3], v.w);
    }
  }
  const float bh0 = (kq == 0) ? bh[r0] : 0.f;
  const float bh1 = (kq == 0) ? bh[r0 + 64] : 0.f;
  const float bh2 = (kq == 0) ? bh[r0 + 128] : 0.f;

  // prologue: stage chunk 0 synchronously (3072 float4 over 512 threads)
  {
    const int lo0 = dir ? 480 : 0;
    const float4* g4 = (const float4*)(gi + (size_t)lo0 * 768);
    float4* l4 = (float4*)gis[0];
    #pragma unroll
    for (int j = 0; j < 6; ++j) {
      const int f = j * 512 + tid;
      const int row = f / 96;
      const int col = f - row * 96;
      l4[f] = g4[row * 192 + col];
    }
  }
  float hreg = 0.f;
  if (tid < 128) hlds[tid] = 0.f;
  LDS_BARRIER();

  const float4* h4q = (const float4*)hlds + kq * 8;
  float4 stg[6];

  for (int c = 0; c < 16; ++c) {
    const int buf = c & 1;
    const int lo = dir ? (480 - 32 * c) : (32 * c);
    // issue next chunk's gi loads (held in regs; consumed at chunk end)
    if (c < 15) {
      const int lon = dir ? (480 - 32 * (c + 1)) : (32 * (c + 1));
      const float4* g4 = (const float4*)(gi + (size_t)lon * 768);
      #pragma unroll
      for (int j = 0; j < 6; ++j) {
        const int f = j * 512 + tid;
        const int row = f / 96;
        const int col = f - row * 96;
        stg[j] = g4[row * 192 + col];
      }
    }

    for (int i = 0; i < 32; ++i) {
      const int sloc = dir ? (31 - i) : i;    // row within chunk
      const int seq = lo + sloc;              // absolute sequence index

      // --- matvec from AGPR-resident weights: 96 read + 96 FMA / lane ---
      float4 A0 = {0.f, 0.f, 0.f, 0.f};
      float4 A1 = {0.f, 0.f, 0.f, 0.f};
      float4 A2 = {0.f, 0.f, 0.f, 0.f};
      #pragma unroll
      for (int kk = 0; kk < 8; ++kk) {
        const float4 hv = h4q[kk];
        float w;
        AGPR_READ(w, aw0[kk * 4 + 0]); A0.x = fmaf(w, hv.x, A0.x);
        AGPR_READ(w, aw0[kk * 4 + 1]); A0.y = fmaf(w, hv.y, A0.y);
        AGPR_READ(w, aw0[kk * 4 + 2]); A0.z = fmaf(w, hv.z, A0.z);
        AGPR_READ(w, aw0[kk * 4 + 3]); A0.w = fmaf(w, hv.w, A0.w);
        AGPR_READ(w, aw1[kk * 4 + 0]); A1.x = fmaf(w, hv.x, A1.x);
        AGPR_READ(w, aw1[kk * 4 + 1]); A1.y = fmaf(w, hv.y, A1.y);
        AGPR_READ(w, aw1[kk * 4 + 2]); A1.z = fmaf(w, hv.z, A1.z);
        AGPR_READ(w, aw1[kk * 4 + 3]); A1.w = fmaf(w, hv.w, A1.w);
        AGPR_READ(w, aw2[kk * 4 + 0]); A2.x = fmaf(w, hv.x, A2.x);
        AGPR_READ(w, aw2[kk * 4 + 1]); A2.y = fmaf(w, hv.y, A2.y);
        AGPR_READ(w, aw2[kk * 4 + 2]); A2.z = fmaf(w, hv.z, A2.z);
        AGPR_READ(w, aw2[kk * 4 + 3]); A2.w = fmaf(w, hv.w, A2.w);
      }
      partl[kq * 384 + r0]       = (A0.x + A0.y) + (A0.z + A0.w) + bh0;
      partl[kq * 384 + r0 + 64]  = (A1.x + A1.y) + (A1.z + A1.w) + bh1;
      partl[kq * 384 + r0 + 128] = (A2.x + A2.y) + (A2.z + A2.w) + bh2;
      LDS_BARRIER();

      if (tid < 128) {
        const float* grow = &gis[buf][sloc * 384];
        const float ghr = (partl[tid]       + partl[384 + tid])
                        + (partl[768 + tid] + partl[1152 + tid]);
        const float ghz = (partl[tid + 128]        + partl[384 + tid + 128])
                        + (partl[768 + tid + 128]  + partl[1152 + tid + 128]);
        const float ghn = (partl[tid + 256]        + partl[384 + tid + 256])
                        + (partl[768 + tid + 256]  + partl[1152 + tid + 256]);
        const float gir = grow[tid];
        const float giz = grow[tid + 128];
        const float gin = grow[tid + 256];
        const float r = __fdividef(1.f, 1.f + __expf(-(gir + ghr)));
        const float z = __fdividef(1.f, 1.f + __expf(-(giz + ghz)));
        float an = gin + r * ghn;
        an = fminf(fmaxf(an, -15.f), 15.f);
        const float t = __expf(2.f * an);
        const float n = __fdividef(t - 1.f, t + 1.f);
        hreg = (1.f - z) * n + z * hreg;
        hlds[tid] = hreg;
        srep[((size_t)(b * 512 + seq)) * 256 + dir * 128 + tid] = hreg;
      }
      LDS_BARRIER();
    }

    // write staged next chunk into the buffer we just finished reading
    if (c < 15) {
      float4* l4 = (float4*)gis[buf ^ 1];
      #pragma unroll
      for (int j = 0; j < 6; ++j) l4[j * 512 + tid] = stg[j];
      LDS_BARRIER();
    }
  }
  if (tid < 128) hfin[(size_t)dir * 4096 + (size_t)b * 128 + tid] = hreg;
}

// ---------------------------------------------------------------------------
// K4: topic boundary diffs.  grid = B*T = 512, 256 threads.
// ---------------------------------------------------------------------------
__global__ __launch_bounds__(256) void k_topic(
    const int* __restrict__ starts, const int* __restrict__ ends,
    const float* __restrict__ srep, float* __restrict__ tmat)
{
  const int bt = blockIdx.x;
  const int b = bt >> 4;
  const int st = starts[bt], en = ends[bt];
  const int j = threadIdx.x;
  float v;
  if (j < 128) {
    const float a = (en >= 1 && en <= 512) ? srep[((size_t)(b * 512 + en - 1)) * 256 + j] : 0.f;
    const float c = (st - 1 >= 1 && st - 1 <= 512) ? srep[((size_t)(b * 512 + st - 2)) * 256 + j] : 0.f;
    v = a - c;
  } else {
    const float a = (st >= 1 && st <= 512) ? srep[((size_t)(b * 512 + st - 1)) * 256 + j] : 0.f;
    const float c = (en + 1 >= 1 && en + 1 <= 512) ? srep[((size_t)(b * 512 + en)) * 256 + j] : 0.f;
    v = a - c;
  }
  tmat[(size_t)bt * 256 + j] = v;
}

// ---------------------------------------------------------------------------
// K6: attention scores + context + assemble decoder input.  grid = B*S.
// ---------------------------------------------------------------------------
__global__ __launch_bounds__(256) void k_scores(
    const float* spart, const float* __restrict__ docp, const float* __restrict__ topp,
    const float* __restrict__ v_att, const float* __restrict__ srep,
    const float* __restrict__ docrep, const float* __restrict__ tmat,
    const int* __restrict__ s2t, float* inp)
{
  const int bs = blockIdx.x;
  const int b = bs >> 9;
  const int tid = threadIdx.x;
  const int tp = s2t[bs];
  const float* sp = spart + (size_t)bs * 512;
  const float* dp = docp + (size_t)b * 512;
  const float* tq = topp + ((size_t)(b * 16 + tp)) * 512;
  float ds = 0.f, ts = 0.f;
  #pragma unroll
  for (int r = 0; r < 2; ++r) {
    const int o = tid + r * 256;
    const float s0 = sp[o], v = v_att[o];
    ds += tanhf(s0 + dp[o]) * v;
    ts += tanhf(s0 + tq[o]) * v;
  }
  #pragma unroll
  for (int off = 32; off; off >>= 1) {
    ds += __shfl_down(ds, off);
    ts += __shfl_down(ts, off);
  }
  __shared__ float rds[4], rts[4], wsh[2];
  const int wv = tid >> 6, ln = tid & 63;
  if (ln == 0) { rds[wv] = ds; rts[wv] = ts; }
  __syncthreads();
  if (tid == 0) {
    const float D = rds[0] + rds[1] + rds[2] + rds[3];
    const float T = rts[0] + rts[1] + rts[2] + rts[3];
    const float sum = D + T;
    wsh[0] = D / sum;
    wsh[1] = T / sum;
  }
  __syncthreads();
  const float dw = wsh[0], tw = wsh[1];
  const float sr = srep[(size_t)bs * 256 + tid];
  const float ctx = dw * docrep[(size_t)b * 256 + tid]
                  + tw * tmat[((size_t)(b * 16 + tp)) * 256 + tid];
  float* op = inp + (size_t)bs * 512;
  op[tid] = sr;
  op[256 + tid] = ctx;
}

// ---------------------------------------------------------------------------
// K8: logits[bs] = dot(hbuf[bs], W2) + b2.  grid = B*S, 64 threads.
// ---------------------------------------------------------------------------
__global__ __launch_bounds__(64) void k_logits(
    const float* __restrict__ hbuf, const float* __restrict__ W2,
    const float* __restrict__ b2, float* __restrict__ out)
{
  const int bs = blockIdx.x;
  const int ln = threadIdx.x;
  const float* h = hbuf + (size_t)bs * 128;
  float a = fmaf(h[ln], W2[ln], h[ln + 64] * W2[ln + 64]);
  #pragma unroll
  for (int off = 32; off; off >>= 1) a += __shfl_down(a, off);
  if (ln == 0) out[bs] = a + b2[0];
}

// ---------------------------------------------------------------------------
extern "C" void kernel_launch(void* const* d_in, const int* in_sizes, int n_in,
                              void* d_out, int out_size, void* d_ws, size_t ws_size,
                              hipStream_t stream)
{
  (void)in_sizes; (void)n_in; (void)out_size;

  const int*   word_ids = (const int*)d_in[0];
  const int*   starts   = (const int*)d_in[1];
  const int*   ends     = (const int*)d_in[2];
  const int*   s2t      = (const int*)d_in[3];
  const float* emb      = (const float*)d_in[4];
  const float* Wi_f     = (const float*)d_in[5];
  const float* Wh_f     = (const float*)d_in[6];
  const float* bi_f     = (const float*)d_in[7];
  const float* bh_f     = (const float*)d_in[8];
  const float* Wi_b     = (const float*)d_in[9];
  const float* Wh_b     = (const float*)d_in[10];
  const float* bi_b     = (const float*)d_in[11];
  const float* bh_b     = (const float*)d_in[12];
  const float* W_att    = (const float*)d_in[13];
  const float* v_att    = (const float*)d_in[14];
  const float* W1       = (const float*)d_in[15];
  const float* b1       = (const float*)d_in[16];
  const float* W2       = (const float*)d_in[17];
  const float* b2       = (const float*)d_in[18];
  float* out = (float*)d_out;

  // Workspace layout (bytes).  Aliasing:
  //   gi_fb (50.3MB) at +19,660,800; spart/inp (33.6MB) overlays it after k_gru
  //   Wcat/bcat (922KB) live at srep's start, dead before k_gru writes srep
  //   hbuf (8.4MB) overlays sent (dead after gi GEMM)
  char* ws = (char*)d_ws;
  if (ws_size < 88440832u) return;   // insufficient scratch -> fail loudly
  float* sent  = (float*)(ws + 0);          // 16384*300*4 = 19,660,800
  float* gi_fb = (float*)(ws + 19660800);   // 16384*768*4 = 50,331,648
  float* srep  = (float*)(ws + 69992448);   // 16384*256*4 = 16,777,216
  float* hfin  = (float*)(ws + 86769664);   // 2*32*128*4  = 32,768  (== doc_rep flat)
  float* tmat  = (float*)(ws + 86802432);   // 32*16*256*4 = 524,288
  float* docp  = (float*)(ws + 87326720);   // 32*512*4    = 65,536
  float* topp  = (float*)(ws + 87392256);   // 512*512*4   = 1,048,576 -> end 88,440,832
  float* spart = (float*)(ws + 19660800);   // alias gi_fb
  float* hbuf  = (float*)(ws + 0);          // alias sent
  float* Wcat  = (float*)(ws + 69992448);   // alias srep head (768*300*4 = 921,600)
  float* bcat  = (float*)(ws + 70914048);   // 768*4, still inside srep region

  // 1) sentence means (float4 gather)
  k_sent_mean<<<16384, 128, 0, stream>>>(word_ids, emb, sent);
  // 1b) concat input-gate weights/biases into ws
  k_wcat<<<450, 256, 0, stream>>>(Wi_f, Wi_b, bi_f, bi_b, Wcat, bcat);
  // 2) fused input gates: gi_fb = sent @ Wcat^T + bcat  (N=768)
  k_gemm<true, 0><<<dim3(128, 6), 256, 0, stream>>>(16384, 768, 300, sent, 300, Wcat, 300, gi_fb, 768, bcat);
  // 3) bidirectional GRU recurrence -> sent_rep (B,S,2H), hfin (2,B,H)
  k_gru<<<64, 512, 0, stream>>>(gi_fb, Wh_f, Wh_b, bh_f, bh_b, srep, hfin);
  // 4) topic boundary matrix
  k_topic<<<512, 256, 0, stream>>>(starts, ends, srep, tmat);
  // 5) attention partial projections (cat@W_att split by halves of W_att rows)
  k_gemm<false, 0><<<dim3(128, 4), 256, 0, stream>>>(16384, 512, 256, srep, 256, W_att + 256 * 512, 512, spart, 512, nullptr);
  k_gemm<false, 0><<<dim3(1, 4),   256, 0, stream>>>(32,    512, 256, hfin, 256, W_att,            512, docp,  512, nullptr);
  k_gemm<false, 0><<<dim3(4, 4),   256, 0, stream>>>(512,   512, 256, tmat, 256, W_att,            512, topp,  512, nullptr);
  // 6) scores -> weights -> context -> decoder input (in-place over spart)
  k_scores<<<16384, 256, 0, stream>>>(spart, docp, topp, v_att, srep, hfin, tmat, s2t, spart);
  // 7) h = relu(inp @ W1^T + b1)
  k_gemm<true, 1><<<dim3(128, 1), 256, 0, stream>>>(16384, 128, 512, spart, 512, W1, 512, hbuf, 128, b1);
  // 8) logits
  k_logits<<<16384, 64, 0, stream>>>(hbuf, W2, b2, out);
}

// Round 14
// 918.852 us; speedup vs baseline: 1.0512x; 1.0512x over previous
//
#include <hip/hip_runtime.h>

// Problem constants: B=32, S=512, L=20, T=16, E=300, H=128, D=128, V=50000

// Raw workgroup barrier: orders LDS ops (lgkmcnt drain) but does NOT drain
// vmcnt — keeps prefetch global-loads and fire-and-forget stores in flight.
// The "memory" clobber also prevents hoisting LDS reads out of the loop.
#define LDS_BARRIER() do {                                   \
    asm volatile("s_waitcnt lgkmcnt(0)" ::: "memory");       \
    __builtin_amdgcn_s_barrier();                            \
    asm volatile("" ::: "memory");                           \
  } while (0)

// ---------------------------------------------------------------------------
// K0: concatenate GRU input-gate weights/biases: Wcat (768,300) = [Wi_f;Wi_b],
// bcat (768) = [bi_f;bi_b].  grid = 450 x 256.
// ---------------------------------------------------------------------------
__global__ __launch_bounds__(256) void k_wcat(
    const float* __restrict__ wf, const float* __restrict__ wb,
    const float* __restrict__ bf, const float* __restrict__ bb,
    float* __restrict__ Wcat, float* __restrict__ bcat)
{
  const int idx = blockIdx.x * 256 + threadIdx.x;   // 0 .. 115199
  Wcat[idx] = wf[idx];
  Wcat[115200 + idx] = wb[idx];
  if (idx < 384) { bcat[idx] = bf[idx]; bcat[384 + idx] = bb[idx]; }
}

// ---------------------------------------------------------------------------
// K1: sentence embedding mean, float4 loads.  grid = B*S blocks, 128 threads.
// ---------------------------------------------------------------------------
__global__ __launch_bounds__(128) void k_sent_mean(
    const int* __restrict__ wid, const float* __restrict__ emb,
    float* __restrict__ sent)
{
  const int bs = blockIdx.x;
  const int t = threadIdx.x;
  const int* w = wid + (size_t)bs * 20;
  if (t >= 75) return;
  float4 a = {0.f, 0.f, 0.f, 0.f};
  for (int l = 0; l < 20; ++l) {
    const float4 v = *(const float4*)(emb + (size_t)w[l] * 300 + t * 4);
    a.x += v.x; a.y += v.y; a.z += v.z; a.w += v.w;
  }
  const float inv = 1.0f / 20.0f;
  a.x *= inv; a.y *= inv; a.z *= inv; a.w *= inv;
  *(float4*)(sent + (size_t)bs * 300 + t * 4) = a;
}

// ---------------------------------------------------------------------------
// K2 v2 (round-12 proven): fp32 tiled GEMM with transposed-A LDS (Ast[k][m]).
// C[M,N] = A[M,K] @ B + bias, optional relu.
// BT=true : B is (N,K) row-major -> C=A@B^T ;  BT=false: B is (K,N) -> C=A@B
// 64x64 tile, 256 threads, 4x4 micro-tile, K chunked by 64.  N % 64 == 0.
// (Round-13's 128x128 v3 regressed — reverted.)
// ---------------------------------------------------------------------------
template<bool BT, int ACT>
__global__ __launch_bounds__(256) void k_gemm(
    const int M, const int N, const int K,
    const float* __restrict__ A, const int lda,
    const float* __restrict__ Bm, const int ldb,
    float* __restrict__ C, const int ldc,
    const float* __restrict__ bias)
{
  (void)N;
  __shared__ float Ast[64][68];   // [k][m] — transposed
  __shared__ float Bs[64][68];    // [k][n]
  const int tid = threadIdx.x;
  const int m0 = blockIdx.x * 64;
  const int n0 = blockIdx.y * 64;
  const int tx = tid & 15;
  const int ty = tid >> 4;
  float acc[4][4] = {};

  for (int kc = 0; kc < K; kc += 64) {
    const int kb = (K - kc < 64) ? (K - kc) : 64;
    #pragma unroll
    for (int r = 0; r < 4; ++r) {
      const int m = r * 16 + ty;
      const int k4 = tx * 4;
      float4 v = make_float4(0.f, 0.f, 0.f, 0.f);
      if (m0 + m < M) {
        const float* ap = A + (size_t)(m0 + m) * lda + kc;
        if (k4 + 4 <= kb) {
          v = *(const float4*)(ap + k4);
        } else {
          float t0 = (k4 + 0 < kb) ? ap[k4 + 0] : 0.f;
          float t1 = (k4 + 1 < kb) ? ap[k4 + 1] : 0.f;
          float t2 = (k4 + 2 < kb) ? ap[k4 + 2] : 0.f;
          float t3 = (k4 + 3 < kb) ? ap[k4 + 3] : 0.f;
          v = make_float4(t0, t1, t2, t3);
        }
      }
      Ast[k4 + 0][m] = v.x;
      Ast[k4 + 1][m] = v.y;
      Ast[k4 + 2][m] = v.z;
      Ast[k4 + 3][m] = v.w;
    }
    if (BT) {
      #pragma unroll
      for (int r = 0; r < 4; ++r) {
        const int n = r * 16 + ty;
        const int k4 = tx * 4;
        float4 v = make_float4(0.f, 0.f, 0.f, 0.f);
        const float* bp = Bm + (size_t)(n0 + n) * ldb + kc;
        if (k4 + 4 <= kb) {
          v = *(const float4*)(bp + k4);
        } else {
          float t0 = (k4 + 0 < kb) ? bp[k4 + 0] : 0.f;
          float t1 = (k4 + 1 < kb) ? bp[k4 + 1] : 0.f;
          float t2 = (k4 + 2 < kb) ? bp[k4 + 2] : 0.f;
          float t3 = (k4 + 3 < kb) ? bp[k4 + 3] : 0.f;
          v = make_float4(t0, t1, t2, t3);
        }
        Bs[k4 + 0][n] = v.x;
        Bs[k4 + 1][n] = v.y;
        Bs[k4 + 2][n] = v.z;
        Bs[k4 + 3][n] = v.w;
      }
    } else {
      #pragma unroll
      for (int r = 0; r < 4; ++r) {
        const int kk = r * 16 + ty;
        const int n4 = tx * 4;
        float4 v = make_float4(0.f, 0.f, 0.f, 0.f);
        if (kk < kb) v = *(const float4*)(Bm + (size_t)(kc + kk) * ldb + n0 + n4);
        *(float4*)&Bs[kk][n4] = v;
      }
    }
    __syncthreads();
    #pragma unroll 4
    for (int kk = 0; kk < kb; ++kk) {
      const float4 av = *(const float4*)&Ast[kk][ty * 4];
      const float4 bv = *(const float4*)&Bs[kk][tx * 4];
      acc[0][0] = fmaf(av.x, bv.x, acc[0][0]);
      acc[0][1] = fmaf(av.x, bv.y, acc[0][1]);
      acc[0][2] = fmaf(av.x, bv.z, acc[0][2]);
      acc[0][3] = fmaf(av.x, bv.w, acc[0][3]);
      acc[1][0] = fmaf(av.y, bv.x, acc[1][0]);
      acc[1][1] = fmaf(av.y, bv.y, acc[1][1]);
      acc[1][2] = fmaf(av.y, bv.z, acc[1][2]);
      acc[1][3] = fmaf(av.y, bv.w, acc[1][3]);
      acc[2][0] = fmaf(av.z, bv.x, acc[2][0]);
      acc[2][1] = fmaf(av.z, bv.y, acc[2][1]);
      acc[2][2] = fmaf(av.z, bv.z, acc[2][2]);
      acc[2][3] = fmaf(av.z, bv.w, acc[2][3]);
      acc[3][0] = fmaf(av.w, bv.x, acc[3][0]);
      acc[3][1] = fmaf(av.w, bv.y, acc[3][1]);
      acc[3][2] = fmaf(av.w, bv.z, acc[3][2]);
      acc[3][3] = fmaf(av.w, bv.w, acc[3][3]);
    }
    __syncthreads();
  }

  float bv4[4] = {0.f, 0.f, 0.f, 0.f};
  if (bias != nullptr) {
    #pragma unroll
    for (int j = 0; j < 4; ++j) bv4[j] = bias[n0 + tx * 4 + j];
  }
  #pragma unroll
  for (int i = 0; i < 4; ++i) {
    const int m = m0 + ty * 4 + i;
    if (m < M) {
      float4 o;
      o.x = acc[i][0] + bv4[0];
      o.y = acc[i][1] + bv4[1];
      o.z = acc[i][2] + bv4[2];
      o.w = acc[i][3] + bv4[3];
      if (ACT == 1) {
        o.x = fmaxf(o.x, 0.f); o.y = fmaxf(o.y, 0.f);
        o.z = fmaxf(o.z, 0.f); o.w = fmaxf(o.w, 0.f);
      }
      *(float4*)&C[(size_t)m * ldc + n0 + tx * 4] = o;
    }
  }
}

// ---------------------------------------------------------------------------
// K3: GRU recurrence — HYBRID LDS/L2 weight streaming.  grid = 64, 512 thr.
//
// Model (rounds 5-13): the step wall is weight BYTES through per-CU pipes;
// the L1-refill path (~128 B/cyc) alone carried all 196 KB/step -> 1530 cyc.
// This version splits the stream across TWO pipes:
//   K[0:64]   (98 KB) LDS-RESIDENT, loaded once (waves kq=0,1 read at
//             256 B/cyc; XOR-swizzled float4 slots -> conflict-free);
//   K[64:128] (98 KB) streamed from L2 per step exactly as round 6
//             (waves kq=2,3; compiler-scheduled, 765 cyc).
// Swizzle: data (row, lslot) stored at (row, lslot ^ (row&7)); lanes read
// logical slot jj -> phys kq*8 + (jj^(ln&7)): 8-lane groups cover all 32
// banks; h4q[jj] stays wave-uniform (broadcast).  Logical k-order unchanged
// -> accumulation bit-identical to round 6 (absmax 0.5).
// gi chunks shrunk 32->16 steps to make LDS room (total 154,112 B).
// 8 waves: kq=wv&3, rg=wv>>2; lane owns rows r0=rg*192+ln, +64, +128.
// partl[4][384]; 2 barriers/step; gi rows stride-768 (fused f/b buffer).
// ---------------------------------------------------------------------------
__global__ __launch_bounds__(512, 2) void k_gru(
    const float* __restrict__ gi_fb,
    const float* __restrict__ Wh_f, const float* __restrict__ Wh_b,
    const float* __restrict__ bh_f, const float* __restrict__ bh_b,
    float* __restrict__ srep, float* __restrict__ hfin)
{
  const int dir = blockIdx.x & 1;
  const int b = blockIdx.x >> 1;
  const float* gi = gi_fb + (size_t)b * 512 * 768 + dir * 384;  // row stride 768
  const float* Wh = dir ? Wh_b : Wh_f;
  const float* bh = dir ? bh_b : bh_f;

  const int tid = threadIdx.x;
  const int wv = tid >> 6;
  const int ln = tid & 63;
  const int kq = wv & 3;          // K-quarter: h floats kq*32 .. kq*32+31
  const int rg = wv >> 2;         // row half: rows rg*192 .. rg*192+191
  const int r0 = rg * 192 + ln;   // this lane's rows: r0, r0+64, r0+128

  __shared__ float4 wlds4[384 * 16];                 // 98,304 B: K[0:64], swizzled
  __shared__ __align__(16) float hlds[128];          // 512 B
  __shared__ float partl[4 * 384];                   // 6,144 B
  __shared__ __align__(16) float gis[2][16 * 384];   // 2 x 24,576 B

  // --- prologue: K[0:64] weights -> LDS, swizzled.  6144 float4 / 512 thr ---
  {
    const float4* Wh4 = (const float4*)Wh;           // 32 float4 per row
    #pragma unroll
    for (int j = 0; j < 12; ++j) {
      const int idx = j * 512 + tid;                 // 0 .. 6143
      const int row = idx >> 4;
      const int lslot = idx & 15;
      wlds4[(row << 4) + (lslot ^ (row & 7))] = Wh4[row * 32 + lslot];
    }
  }

  // --- streamed-path weights (K[64:128]) for kq=2,3: round-6 reg loads ---
  float4 w0[8], w1[8], w2[8];
  if (kq >= 2) {
    const float* p = Wh + (size_t)r0 * 128 + 64 + (kq - 2) * 32;
    #pragma unroll
    for (int kk = 0; kk < 8; ++kk) w0[kk] = *(const float4*)(p + kk * 4);
    p += 64 * 128;
    #pragma unroll
    for (int kk = 0; kk < 8; ++kk) w1[kk] = *(const float4*)(p + kk * 4);
    p += 64 * 128;
    #pragma unroll
    for (int kk = 0; kk < 8; ++kk) w2[kk] = *(const float4*)(p + kk * 4);
  }
  const float bh0 = (kq == 0) ? bh[r0] : 0.f;
  const float bh1 = (kq == 0) ? bh[r0 + 64] : 0.f;
  const float bh2 = (kq == 0) ? bh[r0 + 128] : 0.f;

  // --- prologue: stage gi chunk 0 (1536 float4 over 512 threads) ---
  {
    const int lo0 = dir ? 496 : 0;
    const float4* g4 = (const float4*)(gi + (size_t)lo0 * 768);
    float4* l4 = (float4*)gis[0];
    #pragma unroll
    for (int j = 0; j < 3; ++j) {
      const int f = j * 512 + tid;
      const int row = f / 96;
      const int col = f - row * 96;
      l4[f] = g4[row * 192 + col];
    }
  }
  float hreg = 0.f;
  if (tid < 128) hlds[tid] = 0.f;
  LDS_BARRIER();

  const float4* h4q = (const float4*)hlds + kq * 8;
  const int sw = ln & 7;
  const float4* wl0 = wlds4 + (r0 << 4) + kq * 8;    // valid for kq<2
  const float4* wl1 = wl0 + (64 << 4);
  const float4* wl2 = wl0 + (128 << 4);
  float4 stg[3];

  for (int c = 0; c < 32; ++c) {
    const int buf = c & 1;
    const int lo = dir ? (496 - 16 * c) : (16 * c);
    // issue next chunk's gi loads (held in regs; consumed at chunk end)
    if (c < 31) {
      const int lon = dir ? (496 - 16 * (c + 1)) : (16 * (c + 1));
      const float4* g4 = (const float4*)(gi + (size_t)lon * 768);
      #pragma unroll
      for (int j = 0; j < 3; ++j) {
        const int f = j * 512 + tid;
        const int row = f / 96;
        const int col = f - row * 96;
        stg[j] = g4[row * 192 + col];
      }
    }

    for (int i = 0; i < 16; ++i) {
      const int sloc = dir ? (15 - i) : i;    // row within chunk
      const int seq = lo + sloc;              // absolute sequence index

      float4 A0 = {0.f, 0.f, 0.f, 0.f};
      float4 A1 = {0.f, 0.f, 0.f, 0.f};
      float4 A2 = {0.f, 0.f, 0.f, 0.f};
      if (kq < 2) {
        // --- LDS-resident weights, swizzled conflict-free b128 reads ---
        #pragma unroll
        for (int jj = 0; jj < 8; ++jj) {
          const float4 hv = h4q[jj];          // wave-uniform broadcast
          const float4 q0 = wl0[jj ^ sw];
          const float4 q1 = wl1[jj ^ sw];
          const float4 q2 = wl2[jj ^ sw];
          A0.x = fmaf(q0.x, hv.x, A0.x);
          A0.y = fmaf(q0.y, hv.y, A0.y);
          A0.z = fmaf(q0.z, hv.z, A0.z);
          A0.w = fmaf(q0.w, hv.w, A0.w);
          A1.x = fmaf(q1.x, hv.x, A1.x);
          A1.y = fmaf(q1.y, hv.y, A1.y);
          A1.z = fmaf(q1.z, hv.z, A1.z);
          A1.w = fmaf(q1.w, hv.w, A1.w);
          A2.x = fmaf(q2.x, hv.x, A2.x);
          A2.y = fmaf(q2.y, hv.y, A2.y);
          A2.z = fmaf(q2.z, hv.z, A2.z);
          A2.w = fmaf(q2.w, hv.w, A2.w);
        }
      } else {
        // --- streamed weights (compiler-managed, round-6 behavior) ---
        #pragma unroll
        for (int kk = 0; kk < 8; ++kk) {
          const float4 hv = h4q[kk];
          A0.x = fmaf(w0[kk].x, hv.x, A0.x);
          A0.y = fmaf(w0[kk].y, hv.y, A0.y);
          A0.z = fmaf(w0[kk].z, hv.z, A0.z);
          A0.w = fmaf(w0[kk].w, hv.w, A0.w);
          A1.x = fmaf(w1[kk].x, hv.x, A1.x);
          A1.y = fmaf(w1[kk].y, hv.y, A1.y);
          A1.z = fmaf(w1[kk].z, hv.z, A1.z);
          A1.w = fmaf(w1[kk].w, hv.w, A1.w);
          A2.x = fmaf(w2[kk].x, hv.x, A2.x);
          A2.y = fmaf(w2[kk].y, hv.y, A2.y);
          A2.z = fmaf(w2[kk].z, hv.z, A2.z);
          A2.w = fmaf(w2[kk].w, hv.w, A2.w);
        }
      }
      partl[kq * 384 + r0]       = (A0.x + A0.y) + (A0.z + A0.w) + bh0;
      partl[kq * 384 + r0 + 64]  = (A1.x + A1.y) + (A1.z + A1.w) + bh1;
      partl[kq * 384 + r0 + 128] = (A2.x + A2.y) + (A2.z + A2.w) + bh2;
      LDS_BARRIER();

      if (tid < 128) {
        const float* grow = &gis[buf][sloc * 384];
        const float ghr = (partl[tid]       + partl[384 + tid])
                        + (partl[768 + tid] + partl[1152 + tid]);
        const float ghz = (partl[tid + 128]        + partl[384 + tid + 128])
                        + (partl[768 + tid + 128]  + partl[1152 + tid + 128]);
        const float ghn = (partl[tid + 256]        + partl[384 + tid + 256])
                        + (partl[768 + tid + 256]  + partl[1152 + tid + 256]);
        const float gir = grow[tid];
        const float giz = grow[tid + 128];
        const float gin = grow[tid + 256];
        const float r = __fdividef(1.f, 1.f + __expf(-(gir + ghr)));
        const float z = __fdividef(1.f, 1.f + __expf(-(giz + ghz)));
        float an = gin + r * ghn;
        an = fminf(fmaxf(an, -15.f), 15.f);
        const float t = __expf(2.f * an);
        const float n = __fdividef(t - 1.f, t + 1.f);
        hreg = (1.f - z) * n + z * hreg;
        hlds[tid] = hreg;
        srep[((size_t)(b * 512 + seq)) * 256 + dir * 128 + tid] = hreg;
      }
      LDS_BARRIER();
    }

    // write staged next chunk into the buffer we just finished reading
    if (c < 31) {
      float4* l4 = (float4*)gis[buf ^ 1];
      #pragma unroll
      for (int j = 0; j < 3; ++j) l4[j * 512 + tid] = stg[j];
      LDS_BARRIER();
    }
  }
  if (tid < 128) hfin[(size_t)dir * 4096 + (size_t)b * 128 + tid] = hreg;
}

// ---------------------------------------------------------------------------
// K4: topic boundary diffs.  grid = B*T = 512, 256 threads.
// ---------------------------------------------------------------------------
__global__ __launch_bounds__(256) void k_topic(
    const int* __restrict__ starts, const int* __restrict__ ends,
    const float* __restrict__ srep, float* __restrict__ tmat)
{
  const int bt = blockIdx.x;
  const int b = bt >> 4;
  const int st = starts[bt], en = ends[bt];
  const int j = threadIdx.x;
  float v;
  if (j < 128) {
    const float a = (en >= 1 && en <= 512) ? srep[((size_t)(b * 512 + en - 1)) * 256 + j] : 0.f;
    const float c = (st - 1 >= 1 && st - 1 <= 512) ? srep[((size_t)(b * 512 + st - 2)) * 256 + j] : 0.f;
    v = a - c;
  } else {
    const float a = (st >= 1 && st <= 512) ? srep[((size_t)(b * 512 + st - 1)) * 256 + j] : 0.f;
    const float c = (en + 1 >= 1 && en + 1 <= 512) ? srep[((size_t)(b * 512 + en)) * 256 + j] : 0.f;
    v = a - c;
  }
  tmat[(size_t)bt * 256 + j] = v;
}

// ---------------------------------------------------------------------------
// K6: attention scores + context + assemble decoder input.  grid = B*S.
// ---------------------------------------------------------------------------
__global__ __launch_bounds__(256) void k_scores(
    const float* spart, const float* __restrict__ docp, const float* __restrict__ topp,
    const float* __restrict__ v_att, const float* __restrict__ srep,
    const float* __restrict__ docrep, const float* __restrict__ tmat,
    const int* __restrict__ s2t, float* inp)
{
  const int bs = blockIdx.x;
  const int b = bs >> 9;
  const int tid = threadIdx.x;
  const int tp = s2t[bs];
  const float* sp = spart + (size_t)bs * 512;
  const float* dp = docp + (size_t)b * 512;
  const float* tq = topp + ((size_t)(b * 16 + tp)) * 512;
  float ds = 0.f, ts = 0.f;
  #pragma unroll
  for (int r = 0; r < 2; ++r) {
    const int o = tid + r * 256;
    const float s0 = sp[o], v = v_att[o];
    ds += tanhf(s0 + dp[o]) * v;
    ts += tanhf(s0 + tq[o]) * v;
  }
  #pragma unroll
  for (int off = 32; off; off >>= 1) {
    ds += __shfl_down(ds, off);
    ts += __shfl_down(ts, off);
  }
  __shared__ float rds[4], rts[4], wsh[2];
  const int wv = tid >> 6, ln = tid & 63;
  if (ln == 0) { rds[wv] = ds; rts[wv] = ts; }
  __syncthreads();
  if (tid == 0) {
    const float D = rds[0] + rds[1] + rds[2] + rds[3];
    const float T = rts[0] + rts[1] + rts[2] + rts[3];
    const float sum = D + T;
    wsh[0] = D / sum;
    wsh[1] = T / sum;
  }
  __syncthreads();
  const float dw = wsh[0], tw = wsh[1];
  const float sr = srep[(size_t)bs * 256 + tid];
  const float ctx = dw * docrep[(size_t)b * 256 + tid]
                  + tw * tmat[((size_t)(b * 16 + tp)) * 256 + tid];
  float* op = inp + (size_t)bs * 512;
  op[tid] = sr;
  op[256 + tid] = ctx;
}

// ---------------------------------------------------------------------------
// K8: logits[bs] = dot(hbuf[bs], W2) + b2.  grid = B*S, 64 threads.
// ---------------------------------------------------------------------------
__global__ __launch_bounds__(64) void k_logits(
    const float* __restrict__ hbuf, const float* __restrict__ W2,
    const float* __restrict__ b2, float* __restrict__ out)
{
  const int bs = blockIdx.x;
  const int ln = threadIdx.x;
  const float* h = hbuf + (size_t)bs * 128;
  float a = fmaf(h[ln], W2[ln], h[ln + 64] * W2[ln + 64]);
  #pragma unroll
  for (int off = 32; off; off >>= 1) a += __shfl_down(a, off);
  if (ln == 0) out[bs] = a + b2[0];
}

// ---------------------------------------------------------------------------
extern "C" void kernel_launch(void* const* d_in, const int* in_sizes, int n_in,
                              void* d_out, int out_size, void* d_ws, size_t ws_size,
                              hipStream_t stream)
{
  (void)in_sizes; (void)n_in; (void)out_size;

  const int*   word_ids = (const int*)d_in[0];
  const int*   starts   = (const int*)d_in[1];
  const int*   ends     = (const int*)d_in[2];
  const int*   s2t      = (const int*)d_in[3];
  const float* emb      = (const float*)d_in[4];
  const float* Wi_f     = (const float*)d_in[5];
  const float* Wh_f     = (const float*)d_in[6];
  const float* bi_f     = (const float*)d_in[7];
  const float* bh_f     = (const float*)d_in[8];
  const float* Wi_b     = (const float*)d_in[9];
  const float* Wh_b     = (const float*)d_in[10];
  const float* bi_b     = (const float*)d_in[11];
  const float* bh_b     = (const float*)d_in[12];
  const float* W_att    = (const float*)d_in[13];
  const float* v_att    = (const float*)d_in[14];
  const float* W1       = (const float*)d_in[15];
  const float* b1       = (const float*)d_in[16];
  const float* W2       = (const float*)d_in[17];
  const float* b2       = (const float*)d_in[18];
  float* out = (float*)d_out;

  // Workspace layout (bytes).  Aliasing:
  //   gi_fb (50.3MB) at +19,660,800; spart/inp (33.6MB) overlays it after k_gru
  //   Wcat/bcat (922KB) live at srep's start, dead before k_gru writes srep
  //   hbuf (8.4MB) overlays sent (dead after gi GEMM)
  char* ws = (char*)d_ws;
  if (ws_size < 88440832u) return;   // insufficient scratch -> fail loudly
  float* sent  = (float*)(ws + 0);          // 16384*300*4 = 19,660,800
  float* gi_fb = (float*)(ws + 19660800);   // 16384*768*4 = 50,331,648
  float* srep  = (float*)(ws + 69992448);   // 16384*256*4 = 16,777,216
  float* hfin  = (float*)(ws + 86769664);   // 2*32*128*4  = 32,768  (== doc_rep flat)
  float* tmat  = (float*)(ws + 86802432);   // 32*16*256*4 = 524,288
  float* docp  = (float*)(ws + 87326720);   // 32*512*4    = 65,536
  float* topp  = (float*)(ws + 87392256);   // 512*512*4   = 1,048,576 -> end 88,440,832
  float* spart = (float*)(ws + 19660800);   // alias gi_fb
  float* hbuf  = (float*)(ws + 0);          // alias sent
  float* Wcat  = (float*)(ws + 69992448);   // alias srep head (768*300*4 = 921,600)
  float* bcat  = (float*)(ws + 70914048);   // 768*4, still inside srep region

  // 1) sentence means (float4 gather)
  k_sent_mean<<<16384, 128, 0, stream>>>(word_ids, emb, sent);
  // 1b) concat input-gate weights/biases into ws
  k_wcat<<<450, 256, 0, stream>>>(Wi_f, Wi_b, bi_f, bi_b, Wcat, bcat);
  // 2) fused input gates: gi_fb = sent @ Wcat^T + bcat  (N=768)
  k_gemm<true, 0><<<dim3(256, 12), 256, 0, stream>>>(16384, 768, 300, sent, 300, Wcat, 300, gi_fb, 768, bcat);
  // 3) bidirectional GRU recurrence -> sent_rep (B,S,2H), hfin (2,B,H)
  k_gru<<<64, 512, 0, stream>>>(gi_fb, Wh_f, Wh_b, bh_f, bh_b, srep, hfin);
  // 4) topic boundary matrix
  k_topic<<<512, 256, 0, stream>>>(starts, ends, srep, tmat);
  // 5) attention partial projections (cat@W_att split by halves of W_att rows)
  k_gemm<false, 0><<<dim3(256, 8), 256, 0, stream>>>(16384, 512, 256, srep, 256, W_att + 256 * 512, 512, spart, 512, nullptr);
  k_gemm<false, 0><<<dim3(1, 8),   256, 0, stream>>>(32,    512, 256, hfin, 256, W_att,            512, docp,  512, nullptr);
  k_gemm<false, 0><<<dim3(8, 8),   256, 0, stream>>>(512,   512, 256, tmat, 256, W_att,            512, topp,  512, nullptr);
  // 6) scores -> weights -> context -> decoder input (in-place over spart)
  k_scores<<<16384, 256, 0, stream>>>(spart, docp, topp, v_att, srep, hfin, tmat, s2t, spart);
  // 7) h = relu(inp @ W1^T + b1)
  k_gemm<true, 1><<<dim3(256, 2), 256, 0, stream>>>(16384, 128, 512, spart, 512, W1, 512, hbuf, 128, b1);
  // 8) logits
  k_logits<<<16384, 64, 0, stream>>>(hbuf, W2, b2, out);
}

// Round 15
// 785.442 us; speedup vs baseline: 1.2298x; 1.1699x over previous
//
#include <hip/hip_runtime.h>

// Problem constants: B=32, S=512, L=20, T=16, E=300, H=128, D=128, V=50000

// Raw workgroup barrier: orders LDS ops (lgkmcnt drain) but does NOT drain
// vmcnt — keeps prefetch global-loads and fire-and-forget stores in flight.
#define LDS_BARRIER() do {                                   \
    asm volatile("s_waitcnt lgkmcnt(0)" ::: "memory");       \
    __builtin_amdgcn_s_barrier();                            \
    asm volatile("" ::: "memory");                           \
  } while (0)

// ---------------------------------------------------------------------------
// K0: concatenate GRU input-gate weights/biases: Wcat (768,300) = [Wi_f;Wi_b],
// bcat (768) = [bi_f;bi_b].  grid = 450 x 256.
// ---------------------------------------------------------------------------
__global__ __launch_bounds__(256) void k_wcat(
    const float* __restrict__ wf, const float* __restrict__ wb,
    const float* __restrict__ bf, const float* __restrict__ bb,
    float* __restrict__ Wcat, float* __restrict__ bcat)
{
  const int idx = blockIdx.x * 256 + threadIdx.x;   // 0 .. 115199
  Wcat[idx] = wf[idx];
  Wcat[115200 + idx] = wb[idx];
  if (idx < 384) { bcat[idx] = bf[idx]; bcat[384 + idx] = bb[idx]; }
}

// ---------------------------------------------------------------------------
// K1: sentence embedding mean, float4 loads.  grid = B*S blocks, 128 threads.
// ---------------------------------------------------------------------------
__global__ __launch_bounds__(128) void k_sent_mean(
    const int* __restrict__ wid, const float* __restrict__ emb,
    float* __restrict__ sent)
{
  const int bs = blockIdx.x;
  const int t = threadIdx.x;
  const int* w = wid + (size_t)bs * 20;
  if (t >= 75) return;
  float4 a = {0.f, 0.f, 0.f, 0.f};
  for (int l = 0; l < 20; ++l) {
    const float4 v = *(const float4*)(emb + (size_t)w[l] * 300 + t * 4);
    a.x += v.x; a.y += v.y; a.z += v.z; a.w += v.w;
  }
  const float inv = 1.0f / 20.0f;
  a.x *= inv; a.y *= inv; a.z *= inv; a.w *= inv;
  *(float4*)(sent + (size_t)bs * 300 + t * 4) = a;
}

// ---------------------------------------------------------------------------
// K2 v4: fp32 tiled GEMM, 128x128 tile, BK=64, 8x8 micro-tile split 4+4 at
// stride 64 (a-reads are 16-lane broadcasts; b-reads 2-way-free), 256 thr.
// Per kk per thread: 4 ds_read_b128 -> 64 FMA (v2 was 2 reads -> 16 FMA,
// 3:1 LDS-bound at ~52 TF; v4 ~67% VALU-fed -> ~105 TF).  BK=64 keeps
// staging/barrier overhead at v2's per-flop level (round-13's BK=32 doubled
// it and regressed).  LDS 67.6 KB -> 2 blocks/CU.
// C[M,N] = A[M,K] @ B + bias, optional relu.
// BT=true : B is (N,K) row-major -> C=A@B^T ;  BT=false: B is (K,N) -> C=A@B
// N must be a multiple of 128 at call sites; M,K arbitrary.
// ---------------------------------------------------------------------------
template<bool BT, int ACT>
__global__ __launch_bounds__(256) void k_gemm(
    const int M, const int N, const int K,
    const float* __restrict__ A, const int lda,
    const float* __restrict__ Bm, const int ldb,
    float* __restrict__ C, const int ldc,
    const float* __restrict__ bias)
{
  (void)N;
  __shared__ float Ast[64][132];   // [k][m] transposed; 132 = 128 + 4 pad
  __shared__ float Bs[64][132];    // [k][n]
  const int tid = threadIdx.x;
  const int m0 = blockIdx.x * 128;
  const int n0 = blockIdx.y * 128;
  const int tx = tid & 15;         // n-dir
  const int ty = tid >> 4;         // m-dir
  float acc[2][4][2][4] = {};      // [ih][i][jh][j]: row ih*64+ty*4+i, col jh*64+tx*4+j

  for (int kc = 0; kc < K; kc += 64) {
    const int kb = (K - kc < 64) ? (K - kc) : 64;
    // --- stage A tile transposed: 2048 float4, f = j*256+tid ---
    #pragma unroll
    for (int j = 0; j < 8; ++j) {
      const int f = j * 256 + tid;
      const int m = f >> 4;                 // 0..127
      const int k4 = (f & 15) * 4;          // 0..60
      float4 v = make_float4(0.f, 0.f, 0.f, 0.f);
      if (m0 + m < M) {
        const float* ap = A + (size_t)(m0 + m) * lda + kc;
        if (k4 + 4 <= kb) {
          v = *(const float4*)(ap + k4);
        } else {
          if (k4 + 0 < kb) v.x = ap[k4 + 0];
          if (k4 + 1 < kb) v.y = ap[k4 + 1];
          if (k4 + 2 < kb) v.z = ap[k4 + 2];
          if (k4 + 3 < kb) v.w = ap[k4 + 3];
        }
      }
      Ast[k4 + 0][m] = v.x;
      Ast[k4 + 1][m] = v.y;
      Ast[k4 + 2][m] = v.z;
      Ast[k4 + 3][m] = v.w;
    }
    // --- stage B tile: Bs[k][n] ---
    if (BT) {
      #pragma unroll
      for (int j = 0; j < 8; ++j) {
        const int f = j * 256 + tid;
        const int n = f >> 4;               // n0+n < N (N % 128 == 0)
        const int k4 = (f & 15) * 4;
        float4 v = make_float4(0.f, 0.f, 0.f, 0.f);
        const float* bp = Bm + (size_t)(n0 + n) * ldb + kc;
        if (k4 + 4 <= kb) {
          v = *(const float4*)(bp + k4);
        } else {
          if (k4 + 0 < kb) v.x = bp[k4 + 0];
          if (k4 + 1 < kb) v.y = bp[k4 + 1];
          if (k4 + 2 < kb) v.z = bp[k4 + 2];
          if (k4 + 3 < kb) v.w = bp[k4 + 3];
        }
        Bs[k4 + 0][n] = v.x;
        Bs[k4 + 1][n] = v.y;
        Bs[k4 + 2][n] = v.z;
        Bs[k4 + 3][n] = v.w;
      }
    } else {
      #pragma unroll
      for (int j = 0; j < 8; ++j) {
        const int f = j * 256 + tid;
        const int kk = f >> 5;              // 0..63
        const int n4 = (f & 31) * 4;        // 0..124
        float4 v = make_float4(0.f, 0.f, 0.f, 0.f);
        if (kk < kb) v = *(const float4*)(Bm + (size_t)(kc + kk) * ldb + n0 + n4);
        *(float4*)&Bs[kk][n4] = v;
      }
    }
    __syncthreads();
    #pragma unroll 4
    for (int kk = 0; kk < kb; ++kk) {
      const float4 a0 = *(const float4*)&Ast[kk][ty * 4];        // 16-lane broadcast
      const float4 a1 = *(const float4*)&Ast[kk][64 + ty * 4];
      const float4 b0 = *(const float4*)&Bs[kk][tx * 4];         // 2-way free
      const float4 b1 = *(const float4*)&Bs[kk][64 + tx * 4];
      const float av[2][4] = {{a0.x, a0.y, a0.z, a0.w}, {a1.x, a1.y, a1.z, a1.w}};
      const float bv[2][4] = {{b0.x, b0.y, b0.z, b0.w}, {b1.x, b1.y, b1.z, b1.w}};
      #pragma unroll
      for (int ih = 0; ih < 2; ++ih)
        #pragma unroll
        for (int i = 0; i < 4; ++i)
          #pragma unroll
          for (int jh = 0; jh < 2; ++jh)
            #pragma unroll
            for (int j = 0; j < 4; ++j)
              acc[ih][i][jh][j] = fmaf(av[ih][i], bv[jh][j], acc[ih][i][jh][j]);
    }
    __syncthreads();
  }

  float bv4[2][4] = {};
  if (bias != nullptr) {
    #pragma unroll
    for (int jh = 0; jh < 2; ++jh)
      #pragma unroll
      for (int j = 0; j < 4; ++j)
        bv4[jh][j] = bias[n0 + jh * 64 + tx * 4 + j];
  }
  #pragma unroll
  for (int ih = 0; ih < 2; ++ih)
    #pragma unroll
    for (int i = 0; i < 4; ++i) {
      const int m = m0 + ih * 64 + ty * 4 + i;
      if (m < M) {
        #pragma unroll
        for (int jh = 0; jh < 2; ++jh) {
          float4 o;
          o.x = acc[ih][i][jh][0] + bv4[jh][0];
          o.y = acc[ih][i][jh][1] + bv4[jh][1];
          o.z = acc[ih][i][jh][2] + bv4[jh][2];
          o.w = acc[ih][i][jh][3] + bv4[jh][3];
          if (ACT == 1) {
            o.x = fmaxf(o.x, 0.f); o.y = fmaxf(o.y, 0.f);
            o.z = fmaxf(o.z, 0.f); o.w = fmaxf(o.w, 0.f);
          }
          *(float4*)&C[(size_t)m * ldc + n0 + jh * 64 + tx * 4] = o;
        }
      }
    }
}

// ---------------------------------------------------------------------------
// K3: GRU recurrence — EXACT round-12 kernel (the validated 352 us / 0.5
// absmax floor).  10 rounds of variants (streaming, laundering, fp16, AGPR,
// hybrid-LDS, wave-scaling) all measured >= this; per-CU weight-byte wall
// on 64 forced CUs.  PERMANENT.
// 8 waves; wave wv: kq=wv&3 (K-quarter), rg=wv>>2 (row half); lane owns rows
// r0=rg*192+ln, +64, +128 x 32-K slice.  partl[4][384]; 2 barriers/step;
// 32-step gi chunks (stride-768 fused buffer) via register staging.
// ---------------------------------------------------------------------------
__global__ __launch_bounds__(512, 2) void k_gru(
    const float* __restrict__ gi_fb,
    const float* __restrict__ Wh_f, const float* __restrict__ Wh_b,
    const float* __restrict__ bh_f, const float* __restrict__ bh_b,
    float* __restrict__ srep, float* __restrict__ hfin)
{
  const int dir = blockIdx.x & 1;
  const int b = blockIdx.x >> 1;
  const float* gi = gi_fb + (size_t)b * 512 * 768 + dir * 384;  // row stride 768
  const float* Wh = dir ? Wh_b : Wh_f;
  const float* bh = dir ? bh_b : bh_f;

  const int tid = threadIdx.x;
  const int wv = tid >> 6;
  const int ln = tid & 63;
  const int kq = wv & 3;          // K-quarter: h floats kq*32 .. kq*32+31
  const int rg = wv >> 2;         // row half: rows rg*192 .. rg*192+191
  const int r0 = rg * 192 + ln;   // this lane's rows: r0, r0+64, r0+128

  __shared__ __align__(16) float hlds[128];
  __shared__ float partl[4 * 384];                   // [kq][row], stride-1 rows
  __shared__ __align__(16) float gis[2][32 * 384];   // 2 x 48 KB

  // per-lane weights: 3 rows x 32-K slice = 24 float4
  float4 w0[8], w1[8], w2[8];
  {
    const float* p = Wh + (size_t)r0 * 128 + kq * 32;
    #pragma unroll
    for (int kk = 0; kk < 8; ++kk) w0[kk] = *(const float4*)(p + kk * 4);
    p += 64 * 128;
    #pragma unroll
    for (int kk = 0; kk < 8; ++kk) w1[kk] = *(const float4*)(p + kk * 4);
    p += 64 * 128;
    #pragma unroll
    for (int kk = 0; kk < 8; ++kk) w2[kk] = *(const float4*)(p + kk * 4);
  }
  const float bh0 = (kq == 0) ? bh[r0] : 0.f;
  const float bh1 = (kq == 0) ? bh[r0 + 64] : 0.f;
  const float bh2 = (kq == 0) ? bh[r0 + 128] : 0.f;

  // gi chunk staging map: flat f = j*512+tid over 3072 float4 of one chunk;
  // row = f/96 (96 float4 per 384-float dir-slice), global row stride 192 f4.
  {
    const int lo0 = dir ? 480 : 0;
    const float4* g4 = (const float4*)(gi + (size_t)lo0 * 768);
    float4* l4 = (float4*)gis[0];
    #pragma unroll
    for (int j = 0; j < 6; ++j) {
      const int f = j * 512 + tid;
      const int row = f / 96;
      const int col = f - row * 96;
      l4[f] = g4[row * 192 + col];
    }
  }
  float hreg = 0.f;
  if (tid < 128) hlds[tid] = 0.f;
  LDS_BARRIER();

  const float4* h4q = (const float4*)hlds + kq * 8;
  float4 stg[6];

  for (int c = 0; c < 16; ++c) {
    const int buf = c & 1;
    const int lo = dir ? (480 - 32 * c) : (32 * c);
    // issue next chunk's gi loads (held in regs; consumed at chunk end)
    if (c < 15) {
      const int lon = dir ? (480 - 32 * (c + 1)) : (32 * (c + 1));
      const float4* g4 = (const float4*)(gi + (size_t)lon * 768);
      #pragma unroll
      for (int j = 0; j < 6; ++j) {
        const int f = j * 512 + tid;
        const int row = f / 96;
        const int col = f - row * 96;
        stg[j] = g4[row * 192 + col];
      }
    }

    for (int i = 0; i < 32; ++i) {
      const int sloc = dir ? (31 - i) : i;    // row within chunk
      const int seq = lo + sloc;              // absolute sequence index

      float4 A0 = {0.f, 0.f, 0.f, 0.f};
      float4 A1 = {0.f, 0.f, 0.f, 0.f};
      float4 A2 = {0.f, 0.f, 0.f, 0.f};
      #pragma unroll
      for (int kk = 0; kk < 8; ++kk) {
        const float4 hv = h4q[kk];              // broadcast b128 -> 12 FMA
        A0.x = fmaf(w0[kk].x, hv.x, A0.x);
        A0.y = fmaf(w0[kk].y, hv.y, A0.y);
        A0.z = fmaf(w0[kk].z, hv.z, A0.z);
        A0.w = fmaf(w0[kk].w, hv.w, A0.w);
        A1.x = fmaf(w1[kk].x, hv.x, A1.x);
        A1.y = fmaf(w1[kk].y, hv.y, A1.y);
        A1.z = fmaf(w1[kk].z, hv.z, A1.z);
        A1.w = fmaf(w1[kk].w, hv.w, A1.w);
        A2.x = fmaf(w2[kk].x, hv.x, A2.x);
        A2.y = fmaf(w2[kk].y, hv.y, A2.y);
        A2.z = fmaf(w2[kk].z, hv.z, A2.z);
        A2.w = fmaf(w2[kk].w, hv.w, A2.w);
      }
      partl[kq * 384 + r0]       = (A0.x + A0.y) + (A0.z + A0.w) + bh0;
      partl[kq * 384 + r0 + 64]  = (A1.x + A1.y) + (A1.z + A1.w) + bh1;
      partl[kq * 384 + r0 + 128] = (A2.x + A2.y) + (A2.z + A2.w) + bh2;
      LDS_BARRIER();

      if (tid < 128) {
        const float* grow = &gis[buf][sloc * 384];
        const float ghr = (partl[tid]       + partl[384 + tid])
                        + (partl[768 + tid] + partl[1152 + tid]);
        const float ghz = (partl[tid + 128]        + partl[384 + tid + 128])
                        + (partl[768 + tid + 128]  + partl[1152 + tid + 128]);
        const float ghn = (partl[tid + 256]        + partl[384 + tid + 256])
                        + (partl[768 + tid + 256]  + partl[1152 + tid + 256]);
        const float gir = grow[tid];
        const float giz = grow[tid + 128];
        const float gin = grow[tid + 256];
        const float r = __fdividef(1.f, 1.f + __expf(-(gir + ghr)));
        const float z = __fdividef(1.f, 1.f + __expf(-(giz + ghz)));
        float an = gin + r * ghn;
        an = fminf(fmaxf(an, -15.f), 15.f);
        const float t = __expf(2.f * an);
        const float n = __fdividef(t - 1.f, t + 1.f);
        hreg = (1.f - z) * n + z * hreg;
        hlds[tid] = hreg;
        srep[((size_t)(b * 512 + seq)) * 256 + dir * 128 + tid] = hreg;
      }
      LDS_BARRIER();
    }

    // write staged next chunk into the buffer we just finished reading
    if (c < 15) {
      float4* l4 = (float4*)gis[buf ^ 1];
      #pragma unroll
      for (int j = 0; j < 6; ++j) l4[j * 512 + tid] = stg[j];
      LDS_BARRIER();
    }
  }
  if (tid < 128) hfin[(size_t)dir * 4096 + (size_t)b * 128 + tid] = hreg;
}

// ---------------------------------------------------------------------------
// K4: topic boundary diffs.  grid = B*T = 512, 256 threads.
// ---------------------------------------------------------------------------
__global__ __launch_bounds__(256) void k_topic(
    const int* __restrict__ starts, const int* __restrict__ ends,
    const float* __restrict__ srep, float* __restrict__ tmat)
{
  const int bt = blockIdx.x;
  const int b = bt >> 4;
  const int st = starts[bt], en = ends[bt];
  const int j = threadIdx.x;
  float v;
  if (j < 128) {
    const float a = (en >= 1 && en <= 512) ? srep[((size_t)(b * 512 + en - 1)) * 256 + j] : 0.f;
    const float c = (st - 1 >= 1 && st - 1 <= 512) ? srep[((size_t)(b * 512 + st - 2)) * 256 + j] : 0.f;
    v = a - c;
  } else {
    const float a = (st >= 1 && st <= 512) ? srep[((size_t)(b * 512 + st - 1)) * 256 + j] : 0.f;
    const float c = (en + 1 >= 1 && en + 1 <= 512) ? srep[((size_t)(b * 512 + en)) * 256 + j] : 0.f;
    v = a - c;
  }
  tmat[(size_t)bt * 256 + j] = v;
}

// ---------------------------------------------------------------------------
// K6: attention scores + context + assemble decoder input.  grid = B*S.
// ---------------------------------------------------------------------------
__global__ __launch_bounds__(256) void k_scores(
    const float* spart, const float* __restrict__ docp, const float* __restrict__ topp,
    const float* __restrict__ v_att, const float* __restrict__ srep,
    const float* __restrict__ docrep, const float* __restrict__ tmat,
    const int* __restrict__ s2t, float* inp)
{
  const int bs = blockIdx.x;
  const int b = bs >> 9;
  const int tid = threadIdx.x;
  const int tp = s2t[bs];
  const float* sp = spart + (size_t)bs * 512;
  const float* dp = docp + (size_t)b * 512;
  const float* tq = topp + ((size_t)(b * 16 + tp)) * 512;
  float ds = 0.f, ts = 0.f;
  #pragma unroll
  for (int r = 0; r < 2; ++r) {
    const int o = tid + r * 256;
    const float s0 = sp[o], v = v_att[o];
    ds += tanhf(s0 + dp[o]) * v;
    ts += tanhf(s0 + tq[o]) * v;
  }
  #pragma unroll
  for (int off = 32; off; off >>= 1) {
    ds += __shfl_down(ds, off);
    ts += __shfl_down(ts, off);
  }
  __shared__ float rds[4], rts[4], wsh[2];
  const int wv = tid >> 6, ln = tid & 63;
  if (ln == 0) { rds[wv] = ds; rts[wv] = ts; }
  __syncthreads();
  if (tid == 0) {
    const float D = rds[0] + rds[1] + rds[2] + rds[3];
    const float T = rts[0] + rts[1] + rts[2] + rts[3];
    const float sum = D + T;
    wsh[0] = D / sum;
    wsh[1] = T / sum;
  }
  __syncthreads();
  const float dw = wsh[0], tw = wsh[1];
  const float sr = srep[(size_t)bs * 256 + tid];
  const float ctx = dw * docrep[(size_t)b * 256 + tid]
                  + tw * tmat[((size_t)(b * 16 + tp)) * 256 + tid];
  float* op = inp + (size_t)bs * 512;
  op[tid] = sr;
  op[256 + tid] = ctx;
}

// ---------------------------------------------------------------------------
// K8: logits[bs] = dot(hbuf[bs], W2) + b2.  grid = B*S, 64 threads.
// ---------------------------------------------------------------------------
__global__ __launch_bounds__(64) void k_logits(
    const float* __restrict__ hbuf, const float* __restrict__ W2,
    const float* __restrict__ b2, float* __restrict__ out)
{
  const int bs = blockIdx.x;
  const int ln = threadIdx.x;
  const float* h = hbuf + (size_t)bs * 128;
  float a = fmaf(h[ln], W2[ln], h[ln + 64] * W2[ln + 64]);
  #pragma unroll
  for (int off = 32; off; off >>= 1) a += __shfl_down(a, off);
  if (ln == 0) out[bs] = a + b2[0];
}

// ---------------------------------------------------------------------------
extern "C" void kernel_launch(void* const* d_in, const int* in_sizes, int n_in,
                              void* d_out, int out_size, void* d_ws, size_t ws_size,
                              hipStream_t stream)
{
  (void)in_sizes; (void)n_in; (void)out_size;

  const int*   word_ids = (const int*)d_in[0];
  const int*   starts   = (const int*)d_in[1];
  const int*   ends     = (const int*)d_in[2];
  const int*   s2t      = (const int*)d_in[3];
  const float* emb      = (const float*)d_in[4];
  const float* Wi_f     = (const float*)d_in[5];
  const float* Wh_f     = (const float*)d_in[6];
  const float* bi_f     = (const float*)d_in[7];
  const float* bh_f     = (const float*)d_in[8];
  const float* Wi_b     = (const float*)d_in[9];
  const float* Wh_b     = (const float*)d_in[10];
  const float* bi_b     = (const float*)d_in[11];
  const float* bh_b     = (const float*)d_in[12];
  const float* W_att    = (const float*)d_in[13];
  const float* v_att    = (const float*)d_in[14];
  const float* W1       = (const float*)d_in[15];
  const float* b1       = (const float*)d_in[16];
  const float* W2       = (const float*)d_in[17];
  const float* b2       = (const float*)d_in[18];
  float* out = (float*)d_out;

  // Workspace layout (bytes).  Aliasing:
  //   gi_fb (50.3MB) at +19,660,800; spart/inp (33.6MB) overlays it after k_gru
  //   Wcat/bcat (922KB) live at srep's start, dead before k_gru writes srep
  //   hbuf (8.4MB) overlays sent (dead after gi GEMM)
  char* ws = (char*)d_ws;
  if (ws_size < 88440832u) return;   // insufficient scratch -> fail loudly
  float* sent  = (float*)(ws + 0);          // 16384*300*4 = 19,660,800
  float* gi_fb = (float*)(ws + 19660800);   // 16384*768*4 = 50,331,648
  float* srep  = (float*)(ws + 69992448);   // 16384*256*4 = 16,777,216
  float* hfin  = (float*)(ws + 86769664);   // 2*32*128*4  = 32,768  (== doc_rep flat)
  float* tmat  = (float*)(ws + 86802432);   // 32*16*256*4 = 524,288
  float* docp  = (float*)(ws + 87326720);   // 32*512*4    = 65,536
  float* topp  = (float*)(ws + 87392256);   // 512*512*4   = 1,048,576 -> end 88,440,832
  float* spart = (float*)(ws + 19660800);   // alias gi_fb
  float* hbuf  = (float*)(ws + 0);          // alias sent
  float* Wcat  = (float*)(ws + 69992448);   // alias srep head (768*300*4 = 921,600)
  float* bcat  = (float*)(ws + 70914048);   // 768*4, still inside srep region

  // 1) sentence means (float4 gather)
  k_sent_mean<<<16384, 128, 0, stream>>>(word_ids, emb, sent);
  // 1b) concat input-gate weights/biases into ws
  k_wcat<<<450, 256, 0, stream>>>(Wi_f, Wi_b, bi_f, bi_b, Wcat, bcat);
  // 2) fused input gates: gi_fb = sent @ Wcat^T + bcat  (N=768)
  k_gemm<true, 0><<<dim3(128, 6), 256, 0, stream>>>(16384, 768, 300, sent, 300, Wcat, 300, gi_fb, 768, bcat);
  // 3) bidirectional GRU recurrence -> sent_rep (B,S,2H), hfin (2,B,H)
  k_gru<<<64, 512, 0, stream>>>(gi_fb, Wh_f, Wh_b, bh_f, bh_b, srep, hfin);
  // 4) topic boundary matrix
  k_topic<<<512, 256, 0, stream>>>(starts, ends, srep, tmat);
  // 5) attention partial projections (cat@W_att split by halves of W_att rows)
  k_gemm<false, 0><<<dim3(128, 4), 256, 0, stream>>>(16384, 512, 256, srep, 256, W_att + 256 * 512, 512, spart, 512, nullptr);
  k_gemm<false, 0><<<dim3(1, 4),   256, 0, stream>>>(32,    512, 256, hfin, 256, W_att,            512, docp,  512, nullptr);
  k_gemm<false, 0><<<dim3(4, 4),   256, 0, stream>>>(512,   512, 256, tmat, 256, W_att,            512, topp,  512, nullptr);
  // 6) scores -> weights -> context -> decoder input (in-place over spart)
  k_scores<<<16384, 256, 0, stream>>>(spart, docp, topp, v_att, srep, hfin, tmat, s2t, spart);
  // 7) h = relu(inp @ W1^T + b1)
  k_gemm<true, 1><<<dim3(128, 1), 256, 0, stream>>>(16384, 128, 512, spart, 512, W1, 512, hbuf, 128, b1);
  // 8) logits
  k_logits<<<16384, 64, 0, stream>>>(hbuf, W2, b2, out);
}

// Round 16
// 693.412 us; speedup vs baseline: 1.3930x; 1.1327x over previous
//
#include <hip/hip_runtime.h>

// Problem constants: B=32, S=512, L=20, T=16, E=300, H=128, D=128, V=50000

// Raw workgroup barrier: orders LDS ops (lgkmcnt drain) but does NOT drain
// vmcnt — keeps prefetch global-loads and fire-and-forget stores in flight.
#define LDS_BARRIER() do {                                   \
    asm volatile("s_waitcnt lgkmcnt(0)" ::: "memory");       \
    __builtin_amdgcn_s_barrier();                            \
    asm volatile("" ::: "memory");                           \
  } while (0)

// ---------------------------------------------------------------------------
// K0: concatenate GRU input-gate weights/biases: Wcat (768,300) = [Wi_f;Wi_b],
// bcat (768) = [bi_f;bi_b].  grid = 450 x 256.
// ---------------------------------------------------------------------------
__global__ __launch_bounds__(256) void k_wcat(
    const float* __restrict__ wf, const float* __restrict__ wb,
    const float* __restrict__ bf, const float* __restrict__ bb,
    float* __restrict__ Wcat, float* __restrict__ bcat)
{
  const int idx = blockIdx.x * 256 + threadIdx.x;   // 0 .. 115199
  Wcat[idx] = wf[idx];
  Wcat[115200 + idx] = wb[idx];
  if (idx < 384) { bcat[idx] = bf[idx]; bcat[384 + idx] = bb[idx]; }
}

// ---------------------------------------------------------------------------
// K1: sentence embedding mean, float4 loads.  grid = B*S blocks, 128 threads.
// ---------------------------------------------------------------------------
__global__ __launch_bounds__(128) void k_sent_mean(
    const int* __restrict__ wid, const float* __restrict__ emb,
    float* __restrict__ sent)
{
  const int bs = blockIdx.x;
  const int t = threadIdx.x;
  const int* w = wid + (size_t)bs * 20;
  if (t >= 75) return;
  float4 a = {0.f, 0.f, 0.f, 0.f};
  for (int l = 0; l < 20; ++l) {
    const float4 v = *(const float4*)(emb + (size_t)w[l] * 300 + t * 4);
    a.x += v.x; a.y += v.y; a.z += v.z; a.w += v.w;
  }
  const float inv = 1.0f / 20.0f;
  a.x *= inv; a.y *= inv; a.z *= inv; a.w *= inv;
  *(float4*)(sent + (size_t)bs * 300 + t * 4) = a;
}

// ---------------------------------------------------------------------------
// K2 v2 (PERMANENT — round-12 proven): fp32 tiled GEMM, transposed-A LDS
// (Ast[k][m]).  64x64 tile, 256 threads, 4x4 micro-tile, K chunked by 64.
// Rounds 13/15 established the 128-wide tiles (v3 BK=32, v4 BK=64) both lose
// ~75 us: halved occupancy (2 blocks/CU, LDS-limited) exposes staging
// barriers that v2's 16 waves/CU hide.  Do not revisit.
// C[M,N] = A[M,K] @ B + bias, optional relu.
// BT=true : B is (N,K) row-major -> C=A@B^T ;  BT=false: B is (K,N) -> C=A@B
// N % 64 == 0 at call sites; M,K arbitrary.
// ---------------------------------------------------------------------------
template<bool BT, int ACT>
__global__ __launch_bounds__(256) void k_gemm(
    const int M, const int N, const int K,
    const float* __restrict__ A, const int lda,
    const float* __restrict__ Bm, const int ldb,
    float* __restrict__ C, const int ldc,
    const float* __restrict__ bias)
{
  (void)N;
  __shared__ float Ast[64][68];   // [k][m] — transposed
  __shared__ float Bs[64][68];    // [k][n]
  const int tid = threadIdx.x;
  const int m0 = blockIdx.x * 64;
  const int n0 = blockIdx.y * 64;
  const int tx = tid & 15;
  const int ty = tid >> 4;
  float acc[4][4] = {};

  for (int kc = 0; kc < K; kc += 64) {
    const int kb = (K - kc < 64) ? (K - kc) : 64;
    #pragma unroll
    for (int r = 0; r < 4; ++r) {
      const int m = r * 16 + ty;
      const int k4 = tx * 4;
      float4 v = make_float4(0.f, 0.f, 0.f, 0.f);
      if (m0 + m < M) {
        const float* ap = A + (size_t)(m0 + m) * lda + kc;
        if (k4 + 4 <= kb) {
          v = *(const float4*)(ap + k4);
        } else {
          float t0 = (k4 + 0 < kb) ? ap[k4 + 0] : 0.f;
          float t1 = (k4 + 1 < kb) ? ap[k4 + 1] : 0.f;
          float t2 = (k4 + 2 < kb) ? ap[k4 + 2] : 0.f;
          float t3 = (k4 + 3 < kb) ? ap[k4 + 3] : 0.f;
          v = make_float4(t0, t1, t2, t3);
        }
      }
      Ast[k4 + 0][m] = v.x;
      Ast[k4 + 1][m] = v.y;
      Ast[k4 + 2][m] = v.z;
      Ast[k4 + 3][m] = v.w;
    }
    if (BT) {
      #pragma unroll
      for (int r = 0; r < 4; ++r) {
        const int n = r * 16 + ty;
        const int k4 = tx * 4;
        float4 v = make_float4(0.f, 0.f, 0.f, 0.f);
        const float* bp = Bm + (size_t)(n0 + n) * ldb + kc;
        if (k4 + 4 <= kb) {
          v = *(const float4*)(bp + k4);
        } else {
          float t0 = (k4 + 0 < kb) ? bp[k4 + 0] : 0.f;
          float t1 = (k4 + 1 < kb) ? bp[k4 + 1] : 0.f;
          float t2 = (k4 + 2 < kb) ? bp[k4 + 2] : 0.f;
          float t3 = (k4 + 3 < kb) ? bp[k4 + 3] : 0.f;
          v = make_float4(t0, t1, t2, t3);
        }
        Bs[k4 + 0][n] = v.x;
        Bs[k4 + 1][n] = v.y;
        Bs[k4 + 2][n] = v.z;
        Bs[k4 + 3][n] = v.w;
      }
    } else {
      #pragma unroll
      for (int r = 0; r < 4; ++r) {
        const int kk = r * 16 + ty;
        const int n4 = tx * 4;
        float4 v = make_float4(0.f, 0.f, 0.f, 0.f);
        if (kk < kb) v = *(const float4*)(Bm + (size_t)(kc + kk) * ldb + n0 + n4);
        *(float4*)&Bs[kk][n4] = v;
      }
    }
    __syncthreads();
    #pragma unroll 4
    for (int kk = 0; kk < kb; ++kk) {
      const float4 av = *(const float4*)&Ast[kk][ty * 4];
      const float4 bv = *(const float4*)&Bs[kk][tx * 4];
      acc[0][0] = fmaf(av.x, bv.x, acc[0][0]);
      acc[0][1] = fmaf(av.x, bv.y, acc[0][1]);
      acc[0][2] = fmaf(av.x, bv.z, acc[0][2]);
      acc[0][3] = fmaf(av.x, bv.w, acc[0][3]);
      acc[1][0] = fmaf(av.y, bv.x, acc[1][0]);
      acc[1][1] = fmaf(av.y, bv.y, acc[1][1]);
      acc[1][2] = fmaf(av.y, bv.z, acc[1][2]);
      acc[1][3] = fmaf(av.y, bv.w, acc[1][3]);
      acc[2][0] = fmaf(av.z, bv.x, acc[2][0]);
      acc[2][1] = fmaf(av.z, bv.y, acc[2][1]);
      acc[2][2] = fmaf(av.z, bv.z, acc[2][2]);
      acc[2][3] = fmaf(av.z, bv.w, acc[2][3]);
      acc[3][0] = fmaf(av.w, bv.x, acc[3][0]);
      acc[3][1] = fmaf(av.w, bv.y, acc[3][1]);
      acc[3][2] = fmaf(av.w, bv.z, acc[3][2]);
      acc[3][3] = fmaf(av.w, bv.w, acc[3][3]);
    }
    __syncthreads();
  }

  float bv4[4] = {0.f, 0.f, 0.f, 0.f};
  if (bias != nullptr) {
    #pragma unroll
    for (int j = 0; j < 4; ++j) bv4[j] = bias[n0 + tx * 4 + j];
  }
  #pragma unroll
  for (int i = 0; i < 4; ++i) {
    const int m = m0 + ty * 4 + i;
    if (m < M) {
      float4 o;
      o.x = acc[i][0] + bv4[0];
      o.y = acc[i][1] + bv4[1];
      o.z = acc[i][2] + bv4[2];
      o.w = acc[i][3] + bv4[3];
      if (ACT == 1) {
        o.x = fmaxf(o.x, 0.f); o.y = fmaxf(o.y, 0.f);
        o.z = fmaxf(o.z, 0.f); o.w = fmaxf(o.w, 0.f);
      }
      *(float4*)&C[(size_t)m * ldc + n0 + tx * 4] = o;
    }
  }
}

// ---------------------------------------------------------------------------
// K3: GRU recurrence — EXACT round-12 kernel (validated 352 us / 0.5 absmax
// floor; 10 variants all >= this — per-CU weight-byte wall on 64 forced CUs).
// PERMANENT.
// 8 waves; wave wv: kq=wv&3 (K-quarter), rg=wv>>2 (row half); lane owns rows
// r0=rg*192+ln, +64, +128 x 32-K slice.  partl[4][384]; 2 barriers/step;
// 32-step gi chunks (stride-768 fused buffer) via register staging.
// ---------------------------------------------------------------------------
__global__ __launch_bounds__(512, 2) void k_gru(
    const float* __restrict__ gi_fb,
    const float* __restrict__ Wh_f, const float* __restrict__ Wh_b,
    const float* __restrict__ bh_f, const float* __restrict__ bh_b,
    float* __restrict__ srep, float* __restrict__ hfin)
{
  const int dir = blockIdx.x & 1;
  const int b = blockIdx.x >> 1;
  const float* gi = gi_fb + (size_t)b * 512 * 768 + dir * 384;  // row stride 768
  const float* Wh = dir ? Wh_b : Wh_f;
  const float* bh = dir ? bh_b : bh_f;

  const int tid = threadIdx.x;
  const int wv = tid >> 6;
  const int ln = tid & 63;
  const int kq = wv & 3;          // K-quarter: h floats kq*32 .. kq*32+31
  const int rg = wv >> 2;         // row half: rows rg*192 .. rg*192+191
  const int r0 = rg * 192 + ln;   // this lane's rows: r0, r0+64, r0+128

  __shared__ __align__(16) float hlds[128];
  __shared__ float partl[4 * 384];                   // [kq][row], stride-1 rows
  __shared__ __align__(16) float gis[2][32 * 384];   // 2 x 48 KB

  // per-lane weights: 3 rows x 32-K slice = 24 float4
  float4 w0[8], w1[8], w2[8];
  {
    const float* p = Wh + (size_t)r0 * 128 + kq * 32;
    #pragma unroll
    for (int kk = 0; kk < 8; ++kk) w0[kk] = *(const float4*)(p + kk * 4);
    p += 64 * 128;
    #pragma unroll
    for (int kk = 0; kk < 8; ++kk) w1[kk] = *(const float4*)(p + kk * 4);
    p += 64 * 128;
    #pragma unroll
    for (int kk = 0; kk < 8; ++kk) w2[kk] = *(const float4*)(p + kk * 4);
  }
  const float bh0 = (kq == 0) ? bh[r0] : 0.f;
  const float bh1 = (kq == 0) ? bh[r0 + 64] : 0.f;
  const float bh2 = (kq == 0) ? bh[r0 + 128] : 0.f;

  // gi chunk staging map: flat f = j*512+tid over 3072 float4 of one chunk;
  // row = f/96 (96 float4 per 384-float dir-slice), global row stride 192 f4.
  {
    const int lo0 = dir ? 480 : 0;
    const float4* g4 = (const float4*)(gi + (size_t)lo0 * 768);
    float4* l4 = (float4*)gis[0];
    #pragma unroll
    for (int j = 0; j < 6; ++j) {
      const int f = j * 512 + tid;
      const int row = f / 96;
      const int col = f - row * 96;
      l4[f] = g4[row * 192 + col];
    }
  }
  float hreg = 0.f;
  if (tid < 128) hlds[tid] = 0.f;
  LDS_BARRIER();

  const float4* h4q = (const float4*)hlds + kq * 8;
  float4 stg[6];

  for (int c = 0; c < 16; ++c) {
    const int buf = c & 1;
    const int lo = dir ? (480 - 32 * c) : (32 * c);
    // issue next chunk's gi loads (held in regs; consumed at chunk end)
    if (c < 15) {
      const int lon = dir ? (480 - 32 * (c + 1)) : (32 * (c + 1));
      const float4* g4 = (const float4*)(gi + (size_t)lon * 768);
      #pragma unroll
      for (int j = 0; j < 6; ++j) {
        const int f = j * 512 + tid;
        const int row = f / 96;
        const int col = f - row * 96;
        stg[j] = g4[row * 192 + col];
      }
    }

    for (int i = 0; i < 32; ++i) {
      const int sloc = dir ? (31 - i) : i;    // row within chunk
      const int seq = lo + sloc;              // absolute sequence index

      float4 A0 = {0.f, 0.f, 0.f, 0.f};
      float4 A1 = {0.f, 0.f, 0.f, 0.f};
      float4 A2 = {0.f, 0.f, 0.f, 0.f};
      #pragma unroll
      for (int kk = 0; kk < 8; ++kk) {
        const float4 hv = h4q[kk];              // broadcast b128 -> 12 FMA
        A0.x = fmaf(w0[kk].x, hv.x, A0.x);
        A0.y = fmaf(w0[kk].y, hv.y, A0.y);
        A0.z = fmaf(w0[kk].z, hv.z, A0.z);
        A0.w = fmaf(w0[kk].w, hv.w, A0.w);
        A1.x = fmaf(w1[kk].x, hv.x, A1.x);
        A1.y = fmaf(w1[kk].y, hv.y, A1.y);
        A1.z = fmaf(w1[kk].z, hv.z, A1.z);
        A1.w = fmaf(w1[kk].w, hv.w, A1.w);
        A2.x = fmaf(w2[kk].x, hv.x, A2.x);
        A2.y = fmaf(w2[kk].y, hv.y, A2.y);
        A2.z = fmaf(w2[kk].z, hv.z, A2.z);
        A2.w = fmaf(w2[kk].w, hv.w, A2.w);
      }
      partl[kq * 384 + r0]       = (A0.x + A0.y) + (A0.z + A0.w) + bh0;
      partl[kq * 384 + r0 + 64]  = (A1.x + A1.y) + (A1.z + A1.w) + bh1;
      partl[kq * 384 + r0 + 128] = (A2.x + A2.y) + (A2.z + A2.w) + bh2;
      LDS_BARRIER();

      if (tid < 128) {
        const float* grow = &gis[buf][sloc * 384];
        const float ghr = (partl[tid]       + partl[384 + tid])
                        + (partl[768 + tid] + partl[1152 + tid]);
        const float ghz = (partl[tid + 128]        + partl[384 + tid + 128])
                        + (partl[768 + tid + 128]  + partl[1152 + tid + 128]);
        const float ghn = (partl[tid + 256]        + partl[384 + tid + 256])
                        + (partl[768 + tid + 256]  + partl[1152 + tid + 256]);
        const float gir = grow[tid];
        const float giz = grow[tid + 128];
        const float gin = grow[tid + 256];
        const float r = __fdividef(1.f, 1.f + __expf(-(gir + ghr)));
        const float z = __fdividef(1.f, 1.f + __expf(-(giz + ghz)));
        float an = gin + r * ghn;
        an = fminf(fmaxf(an, -15.f), 15.f);
        const float t = __expf(2.f * an);
        const float n = __fdividef(t - 1.f, t + 1.f);
        hreg = (1.f - z) * n + z * hreg;
        hlds[tid] = hreg;
        srep[((size_t)(b * 512 + seq)) * 256 + dir * 128 + tid] = hreg;
      }
      LDS_BARRIER();
    }

    // write staged next chunk into the buffer we just finished reading
    if (c < 15) {
      float4* l4 = (float4*)gis[buf ^ 1];
      #pragma unroll
      for (int j = 0; j < 6; ++j) l4[j * 512 + tid] = stg[j];
      LDS_BARRIER();
    }
  }
  if (tid < 128) hfin[(size_t)dir * 4096 + (size_t)b * 128 + tid] = hreg;
}

// ---------------------------------------------------------------------------
// K4: topic boundary diffs.  grid = B*T = 512, 256 threads.
// ---------------------------------------------------------------------------
__global__ __launch_bounds__(256) void k_topic(
    const int* __restrict__ starts, const int* __restrict__ ends,
    const float* __restrict__ srep, float* __restrict__ tmat)
{
  const int bt = blockIdx.x;
  const int b = bt >> 4;
  const int st = starts[bt], en = ends[bt];
  const int j = threadIdx.x;
  float v;
  if (j < 128) {
    const float a = (en >= 1 && en <= 512) ? srep[((size_t)(b * 512 + en - 1)) * 256 + j] : 0.f;
    const float c = (st - 1 >= 1 && st - 1 <= 512) ? srep[((size_t)(b * 512 + st - 2)) * 256 + j] : 0.f;
    v = a - c;
  } else {
    const float a = (st >= 1 && st <= 512) ? srep[((size_t)(b * 512 + st - 1)) * 256 + j] : 0.f;
    const float c = (en + 1 >= 1 && en + 1 <= 512) ? srep[((size_t)(b * 512 + en)) * 256 + j] : 0.f;
    v = a - c;
  }
  tmat[(size_t)bt * 256 + j] = v;
}

// ---------------------------------------------------------------------------
// K6: attention scores + context + assemble decoder input.  grid = B*S.
// ---------------------------------------------------------------------------
__global__ __launch_bounds__(256) void k_scores(
    const float* spart, const float* __restrict__ docp, const float* __restrict__ topp,
    const float* __restrict__ v_att, const float* __restrict__ srep,
    const float* __restrict__ docrep, const float* __restrict__ tmat,
    const int* __restrict__ s2t, float* inp)
{
  const int bs = blockIdx.x;
  const int b = bs >> 9;
  const int tid = threadIdx.x;
  const int tp = s2t[bs];
  const float* sp = spart + (size_t)bs * 512;
  const float* dp = docp + (size_t)b * 512;
  const float* tq = topp + ((size_t)(b * 16 + tp)) * 512;
  float ds = 0.f, ts = 0.f;
  #pragma unroll
  for (int r = 0; r < 2; ++r) {
    const int o = tid + r * 256;
    const float s0 = sp[o], v = v_att[o];
    ds += tanhf(s0 + dp[o]) * v;
    ts += tanhf(s0 + tq[o]) * v;
  }
  #pragma unroll
  for (int off = 32; off; off >>= 1) {
    ds += __shfl_down(ds, off);
    ts += __shfl_down(ts, off);
  }
  __shared__ float rds[4], rts[4], wsh[2];
  const int wv = tid >> 6, ln = tid & 63;
  if (ln == 0) { rds[wv] = ds; rts[wv] = ts; }
  __syncthreads();
  if (tid == 0) {
    const float D = rds[0] + rds[1] + rds[2] + rds[3];
    const float T = rts[0] + rts[1] + rts[2] + rts[3];
    const float sum = D + T;
    wsh[0] = D / sum;
    wsh[1] = T / sum;
  }
  __syncthreads();
  const float dw = wsh[0], tw = wsh[1];
  const float sr = srep[(size_t)bs * 256 + tid];
  const float ctx = dw * docrep[(size_t)b * 256 + tid]
                  + tw * tmat[((size_t)(b * 16 + tp)) * 256 + tid];
  float* op = inp + (size_t)bs * 512;
  op[tid] = sr;
  op[256 + tid] = ctx;
}

// ---------------------------------------------------------------------------
// K8: logits[bs] = dot(hbuf[bs], W2) + b2.  grid = B*S, 64 threads.
// ---------------------------------------------------------------------------
__global__ __launch_bounds__(64) void k_logits(
    const float* __restrict__ hbuf, const float* __restrict__ W2,
    const float* __restrict__ b2, float* __restrict__ out)
{
  const int bs = blockIdx.x;
  const int ln = threadIdx.x;
  const float* h = hbuf + (size_t)bs * 128;
  float a = fmaf(h[ln], W2[ln], h[ln + 64] * W2[ln + 64]);
  #pragma unroll
  for (int off = 32; off; off >>= 1) a += __shfl_down(a, off);
  if (ln == 0) out[bs] = a + b2[0];
}

// ---------------------------------------------------------------------------
extern "C" void kernel_launch(void* const* d_in, const int* in_sizes, int n_in,
                              void* d_out, int out_size, void* d_ws, size_t ws_size,
                              hipStream_t stream)
{
  (void)in_sizes; (void)n_in; (void)out_size;

  const int*   word_ids = (const int*)d_in[0];
  const int*   starts   = (const int*)d_in[1];
  const int*   ends     = (const int*)d_in[2];
  const int*   s2t      = (const int*)d_in[3];
  const float* emb      = (const float*)d_in[4];
  const float* Wi_f     = (const float*)d_in[5];
  const float* Wh_f     = (const float*)d_in[6];
  const float* bi_f     = (const float*)d_in[7];
  const float* bh_f     = (const float*)d_in[8];
  const float* Wi_b     = (const float*)d_in[9];
  const float* Wh_b     = (const float*)d_in[10];
  const float* bi_b     = (const float*)d_in[11];
  const float* bh_b     = (const float*)d_in[12];
  const float* W_att    = (const float*)d_in[13];
  const float* v_att    = (const float*)d_in[14];
  const float* W1       = (const float*)d_in[15];
  const float* b1       = (const float*)d_in[16];
  const float* W2       = (const float*)d_in[17];
  const float* b2       = (const float*)d_in[18];
  float* out = (float*)d_out;

  // Workspace layout (bytes).  Aliasing:
  //   gi_fb (50.3MB) at +19,660,800; spart/inp (33.6MB) overlays it after k_gru
  //   Wcat/bcat (922KB) live at srep's start, dead before k_gru writes srep
  //   hbuf (8.4MB) overlays sent (dead after gi GEMM)
  // Contiguity exploited by the merged decoder GEMM:
  //   srep | hfin | tmat are contiguous rows of 256 floats (A, M=16928 view);
  //   docp | topp are contiguous rows of 512 floats (C, M=544 view).
  char* ws = (char*)d_ws;
  if (ws_size < 88440832u) return;   // insufficient scratch -> fail loudly
  float* sent  = (float*)(ws + 0);          // 16384*300*4 = 19,660,800
  float* gi_fb = (float*)(ws + 19660800);   // 16384*768*4 = 50,331,648
  float* srep  = (float*)(ws + 69992448);   // 16384*256*4 = 16,777,216
  float* hfin  = (float*)(ws + 86769664);   // 2*32*128*4  = 32,768  (== doc_rep flat)
  float* tmat  = (float*)(ws + 86802432);   // 32*16*256*4 = 524,288
  float* docp  = (float*)(ws + 87326720);   // 32*512*4    = 65,536
  float* topp  = (float*)(ws + 87392256);   // 512*512*4   = 1,048,576 -> end 88,440,832
  float* spart = (float*)(ws + 19660800);   // alias gi_fb
  float* hbuf  = (float*)(ws + 0);          // alias sent
  float* Wcat  = (float*)(ws + 69992448);   // alias srep head (768*300*4 = 921,600)
  float* bcat  = (float*)(ws + 70914048);   // 768*4, still inside srep region

  // 1) sentence means (float4 gather)
  k_sent_mean<<<16384, 128, 0, stream>>>(word_ids, emb, sent);
  // 1b) concat input-gate weights/biases into ws
  k_wcat<<<450, 256, 0, stream>>>(Wi_f, Wi_b, bi_f, bi_b, Wcat, bcat);
  // 2) fused input gates: gi_fb = sent @ Wcat^T + bcat  (N=768)
  k_gemm<true, 0><<<dim3(256, 12), 256, 0, stream>>>(16384, 768, 300, sent, 300, Wcat, 300, gi_fb, 768, bcat);
  // 3) bidirectional GRU recurrence -> sent_rep (B,S,2H), hfin (2,B,H)
  k_gru<<<64, 512, 0, stream>>>(gi_fb, Wh_f, Wh_b, bh_f, bh_b, srep, hfin);
  // 4) topic boundary matrix
  k_topic<<<512, 256, 0, stream>>>(starts, ends, srep, tmat);
  // 5) attention partial projections:
  //    spart = srep @ W_att[256:512,:]   (sent-part, 16384 rows)
  //    [docp|topp] = [hfin|tmat] @ W_att[0:256,:]  (merged: M=544, A and C
  //    regions are contiguous in ws — saves the tiny dim3(1,8) dispatch)
  k_gemm<false, 0><<<dim3(256, 8), 256, 0, stream>>>(16384, 512, 256, srep, 256, W_att + 256 * 512, 512, spart, 512, nullptr);
  k_gemm<false, 0><<<dim3(9, 8),   256, 0, stream>>>(544,   512, 256, hfin, 256, W_att,            512, docp,  512, nullptr);
  // 6) scores -> weights -> context -> decoder input (in-place over spart)
  k_scores<<<16384, 256, 0, stream>>>(spart, docp, topp, v_att, srep, hfin, tmat, s2t, spart);
  // 7) h = relu(inp @ W1^T + b1)
  k_gemm<true, 1><<<dim3(256, 2), 256, 0, stream>>>(16384, 128, 512, spart, 512, W1, 512, hbuf, 128, b1);
  // 8) logits
  k_logits<<<16384, 64, 0, stream>>>(hbuf, W2, b2, out);
}